// Round 4
// baseline (374.240 us; speedup 1.0000x reference)
//
#include <hip/hip_runtime.h>
#include <math.h>

#define NPTS 524288
#define HALF (NPTS / 2)
#define TSZ  524288
#define TMASK (TSZ - 1)

typedef __attribute__((ext_vector_type(8))) short v8s;   // 8 x bf16 (4 VGPR)
typedef __attribute__((ext_vector_type(4))) float v4f;   // MFMA C/D frag

#define MFMA16(a, b, c) __builtin_amdgcn_mfma_f32_16x16x32_bf16(a, b, c, 0, 0, 0)

__device__ __constant__ float NLf[16] = {
    16.f, 22.f, 30.f, 42.f, 58.f, 80.f, 110.f, 152.f,
    209.f, 288.f, 397.f, 547.f, 754.f, 1039.f, 1432.f, 1974.f
};

#define CEILX 0xE2
#define CEILY 0xD4
#define CEILZ 0xB8

__device__ __forceinline__ short bf16r(float v) {  // f32 -> bf16 RNE
    unsigned b = __float_as_uint(v);
    b += 0x7FFFu + ((b >> 16) & 1u);
    return (short)(b >> 16);
}
__device__ __forceinline__ unsigned packbf(float a, float b) {
    return (unsigned)(unsigned short)bf16r(a) | ((unsigned)(unsigned short)bf16r(b) << 16);
}
__device__ __forceinline__ unsigned sel4(uint4 t, unsigned i) {
    const unsigned ab = (i & 1u) ? t.y : t.x;
    const unsigned cd = (i & 1u) ? t.w : t.z;
    return (i & 2u) ? cd : ab;
}

// ---- kernel 0: pack fp32 tables -> bf16x2; init idx sentinel + counter -----
__global__ __launch_bounds__(256) void pack_tables(
    const float4* __restrict__ tbl, uint2* __restrict__ out,
    unsigned* __restrict__ idxbuf, unsigned* __restrict__ cnt)
{
    const int idx = blockIdx.x * 256 + threadIdx.x;   // handles 2 entries
    const float4 t = tbl[idx];
    out[idx] = make_uint2(packbf(t.x, t.y), packbf(t.z, t.w));
    if (idx < NPTS) idxbuf[idx] = 0xFFFFFFFFu;        // sentinel for tail tiles
    if (idx == 0) cnt[0] = 0u;
}

// ---- kernel 0b: mask + stream compaction -----------------------------------
// 35% of points are outside the box (P(active)=erf(1.5/sqrt2)^3=0.650): their
// outputs are exactly zero -> write zeros here, skip hash+MLP entirely.
// Active points get compacted idx + compacted coords (keeps hash x-staging
// coalesced). Order across waves is nondeterministic (atomic) but per-point
// results are order-independent (MFMA rows independent; gather per-point).
__global__ __launch_bounds__(256) void ngp_compact(
    const float* __restrict__ x, unsigned* __restrict__ idxbuf,
    float* __restrict__ xc, unsigned* __restrict__ cnt,
    float* __restrict__ out)
{
    const int i = blockIdx.x * 256 + threadIdx.x;
    const float x0 = x[3*i+0], x1 = x[3*i+1], x2 = x[3*i+2];
    const float xs0 = x0 / 3.0f, xs1 = x1 / 3.0f, xs2 = x2 / 3.0f;
    const bool act = (fabsf(xs0) < 0.5f) && (fabsf(xs1) < 0.5f) && (fabsf(xs2) < 0.5f);
    if (!act) {
        out[3*i+0] = 0.f; out[3*i+1] = 0.f; out[3*i+2] = 0.f;
        out[3*NPTS + i] = 0.f;
    }
    const unsigned long long mb = __ballot(act);
    const int lane = threadIdx.x & 63;
    int base = 0;
    if (lane == 0) base = (int)atomicAdd(cnt, (unsigned)__popcll(mb));
    base = __shfl(base, 0);
    if (act) {
        const unsigned r = (unsigned)base + (unsigned)__popcll(mb & ((1ull << lane) - 1ull));
        idxbuf[r] = (unsigned)i;
        xc[3*r+0] = x0; xc[3*r+1] = x1; xc[3*r+2] = x2;
    }
}

// ---- kernel 1: hash gather on compacted points (R0 body, level-phased) -----
__global__ __launch_bounds__(256) void ngp_hash5(
    const float* __restrict__ xc, const unsigned* __restrict__ tables_pk,
    const unsigned* __restrict__ cnt, unsigned* __restrict__ feats_pk)
{
    __shared__ float sX[768];
    const int NC = (int)cnt[0];
    if (blockIdx.x * 256 >= NC) return;       // compacted tail: nothing to do

    const int tid = threadIdx.x;
    const int l = blockIdx.y;
    const float n = NLf[l];
    const unsigned* tbl = tables_pk + (size_t)l * TSZ;

    for (int r = tid; r < 768; r += 256)
        sX[r] = xc[(size_t)blockIdx.x * 768 + r];
    __syncthreads();

    const int j = blockIdx.x * 256 + tid;     // compact index (may be >= NC:
                                              // garbage in, garbage out, unused)
    const float xu0 = sX[tid * 3 + 0] / 3.0f + 0.5f;
    const float xu1 = sX[tid * 3 + 1] / 3.0f + 0.5f;
    const float xu2 = sX[tid * 3 + 2] / 3.0f + 0.5f;

    const float p0 = xu0 * n, p1 = xu1 * n, p2 = xu2 * n;
    const float f0 = floorf(p0), f1 = floorf(p1), f2 = floorf(p2);
    const float fr0 = p0 - f0, fr1 = p1 - f1, fr2 = p2 - f2;
    const float g0 = 1.f - fr0, g1 = 1.f - fr1, g2 = 1.f - fr2;
    const unsigned uvf0 = (unsigned)(int)f0;
    const unsigned uvc0 = (unsigned)(int)ceilf(p0);
    const unsigned syf = (unsigned)(int)f1 * 2654435761u;
    const unsigned syc = (unsigned)(int)ceilf(p1) * 2654435761u;
    const unsigned szf = (unsigned)(int)f2 * 805459861u;
    const unsigned szc = (unsigned)(int)ceilf(p2) * 805459861u;

    const float w0 = g0 * g1 * g2,  w1 = fr0 * g1 * g2;
    const float w2 = g0 * fr1 * g2, w6 = g0 * fr1 * fr2;
    const float w3 = fr0 * fr1 * g2, w5 = fr0 * g1 * fr2;
    const float w4 = g0 * g1 * fr2, w7 = fr0 * fr1 * fr2;

    const unsigned Ss[4] = { syf ^ szf, syc ^ szf, syf ^ szc, syc ^ szc };
    const float wf[4] = { w0, w2, w3, w4 };
    const float wc[4] = { w1, w6, w5, w7 };

    float a0 = 0.f, a1 = 0.f;
    #pragma unroll
    for (int pr = 0; pr < 4; ++pr) {
        const unsigned hf = (Ss[pr] ^ uvf0) & TMASK;
        const unsigned hc = (Ss[pr] ^ uvc0) & TMASK;
        const unsigned diff = hf ^ hc;
        const uint4 tv = *(const uint4*)(tbl + (hf & ~3u));
        const unsigned ef = sel4(tv, hf & 3u);
        unsigned ec;
        if (diff <= 3u) ec = sel4(tv, hc & 3u);
        else            ec = tbl[hc];
        a0 = fmaf(wf[pr], __uint_as_float(ef << 16), a0);
        a1 = fmaf(wf[pr], __uint_as_float(ef & 0xFFFF0000u), a1);
        a0 = fmaf(wc[pr], __uint_as_float(ec << 16), a0);
        a1 = fmaf(wc[pr], __uint_as_float(ec & 0xFFFF0000u), a1);
    }
    feats_pk[(size_t)l * NPTS + j] = packbf(a0, a1);
}

// ---- kernel 2: MFMA MLP on compacted points --------------------------------
// R3 structure (swizzled sZ, 1 tile/wave, 8 waves/block); PE precompute
// dropped (R3: no gain, absmax drift) -> posenc in-kernel, bit-identical
// expressions. All compacted points are active: no mask logic; outputs
// scattered through idx; tail rows (idx sentinel) don't store.
#define PZ 72   // z-buffer pitch in shorts (144 B, 16B-aligned)
#define SWL(row) ((((row) >> 2) & 3) << 4)

__global__ __launch_bounds__(512) void ngp_mlp4(
    const float* __restrict__ d,
    const unsigned* __restrict__ feats_pk, const unsigned* __restrict__ idxbuf,
    const unsigned* __restrict__ cnt,
    const float* __restrict__ w1a, const float* __restrict__ b1a,
    const float* __restrict__ w1b, const float* __restrict__ b1b,
    const float* __restrict__ w2a, const float* __restrict__ b2a,
    const float* __restrict__ w2b, const float* __restrict__ b2b,
    const float* __restrict__ w2c, const float* __restrict__ b2c,
    float* __restrict__ out)
{
    __shared__ short sW1a[64 * 40];
    __shared__ short sW1b[16 * 72];
    __shared__ short sW2a[64 * 72];
    __shared__ short sW2b[64 * 72];
    __shared__ short sW2c[16 * 72];
    __shared__ short sZ[8 * 16 * PZ];

    const int NC = (int)cnt[0];
    if (blockIdx.x * 128 >= NC) return;       // whole block beyond compact set

    const int tid = threadIdx.x;

    for (int idx = tid; idx < 32 * 64; idx += 512) {
        const int k = idx >> 6, n2 = idx & 63;
        sW1a[n2 * 40 + k] = bf16r(w1a[k * 64 + n2]);
    }
    for (int idx = tid; idx < 64 * 16; idx += 512) {
        const int k = idx >> 4, n2 = idx & 15;
        sW1b[n2 * 72 + k] = bf16r(w1b[k * 16 + n2]);
    }
    for (int idx = tid; idx < 64 * 64; idx += 512) {
        const int k = idx >> 6, n2 = idx & 63;
        sW2a[n2 * 72 + k] = bf16r(k < 43 ? w2a[k * 64 + n2] : 0.f);
    }
    for (int idx = tid; idx < 64 * 64; idx += 512) {
        const int k = idx >> 6, n2 = idx & 63;
        sW2b[n2 * 72 + k] = bf16r(w2b[k * 64 + n2]);
    }
    for (int idx = tid; idx < 64 * 16; idx += 512) {
        const int k = idx >> 4, n2 = idx & 15;
        sW2c[n2 * 72 + k] = bf16r(n2 < 3 ? w2c[k * 3 + n2] : 0.f);
    }
    __syncthreads();

    const int wave = tid >> 6, lane = tid & 63;
    const int m = lane & 15, q = lane >> 4;
    short* zb = &sZ[wave * 16 * PZ];

    const int j0 = (blockIdx.x * 8 + wave) * 16;   // this wave's compact tile
    if (j0 >= NC) return;                          // after staging+sync: safe

    float bb1a[4], bb2a[4], bb2b[4];
    #pragma unroll
    for (int ct = 0; ct < 4; ++ct) {
        bb1a[ct] = b1a[ct * 16 + m];
        bb2a[ct] = b2a[ct * 16 + m];
        bb2b[ct] = b2b[ct * 16 + m];
    }
    const float bb1b = b1b[m];
    const float bb2c = (m < 3) ? b2c[m] : 0.f;

    // ---- feats -> z cols [0,32), swizzled ------------------------------
    #pragma unroll
    for (int it = 0; it < 4; ++it) {
        const int l = it * 4 + q;
        *(unsigned*)(zb + m * PZ + ((2 * l) ^ SWL(m))) =
            feats_pk[(size_t)l * NPTS + j0 + m];
    }

    // ---- layer 1a: feats(32) -> 64, relu --------------------------------
    {
        const v8s a0 = *(const v8s*)(zb + m * PZ + ((q * 8) ^ SWL(m)));
        #pragma unroll
        for (int ct = 0; ct < 4; ++ct) {
            const float bv = bb1a[ct];
            v4f acc = {bv, bv, bv, bv};
            acc = MFMA16(a0, *(const v8s*)(sW1a + (ct * 16 + m) * 40 + q * 8), acc);
            #pragma unroll
            for (int r = 0; r < 4; ++r)
                zb[(q * 4 + r) * PZ + ((ct * 16 + m) ^ (q << 4))] = bf16r(fmaxf(acc[r], 0.f));
        }
    }

    // ---- layer 1b: 64 -> 16 (h; h[0] is log_sigma) ----------------------
    v4f hacc;
    {
        const v8s a10 = *(const v8s*)(zb + m * PZ + ((q * 8) ^ SWL(m)));
        const v8s a11 = *(const v8s*)(zb + m * PZ + ((32 + q * 8) ^ SWL(m)));
        v4f hv = {bb1b, bb1b, bb1b, bb1b};
        hv = MFMA16(a10, *(const v8s*)(sW1b + m * 72 + q * 8), hv);
        hv = MFMA16(a11, *(const v8s*)(sW1b + m * 72 + 32 + q * 8), hv);
        hacc = hv;
        #pragma unroll
        for (int r = 0; r < 4; ++r)
            zb[(q * 4 + r) * PZ + (m ^ (q << 4))] = bf16r(hv[r]);
    }

    // ---- posenc(d) into z cols [16,43), zero pad [48,64) ----------------
    {
        const unsigned pj = idxbuf[j0 + m];
        const unsigned ps = (pj < (unsigned)NPTS) ? pj : 0u;
        const float dd0 = d[3*ps+0], dd1 = d[3*ps+1], dd2 = d[3*ps+2];
        v8s pk;
        #pragma unroll
        for (int jj = 0; jj < 8; ++jj) {
            const int k = 16 + q * 8 + jj;
            float v;
            if (k < 19) {
                v = (k == 16) ? dd0 : ((k == 17) ? dd1 : dd2);
            } else if (k < 43) {
                const int idx = k - 19;
                const int e = idx / 6, w = idx - 6 * e;
                const float base = (w == 0 || w == 3) ? dd0 : ((w == 1 || w == 4) ? dd1 : dd2);
                const float s = (float)(1 << e) * base;
                v = (w < 3) ? __sinf(s) : __cosf(s);
            } else {
                v = 0.f;
            }
            pk[jj] = bf16r(v);
        }
        *(v8s*)(zb + m * PZ + ((16 + q * 8) ^ SWL(m))) = pk;
        *(unsigned long long*)(zb + m * PZ + ((48 + q * 4) ^ SWL(m))) = 0ull;
    }

    // ---- layer 2a: z(43,pad64) -> 64, relu ------------------------------
    {
        const v8s a20 = *(const v8s*)(zb + m * PZ + ((q * 8) ^ SWL(m)));
        const v8s a21 = *(const v8s*)(zb + m * PZ + ((32 + q * 8) ^ SWL(m)));
        #pragma unroll
        for (int ct = 0; ct < 4; ++ct) {
            const float bv = bb2a[ct];
            v4f acc = {bv, bv, bv, bv};
            acc = MFMA16(a20, *(const v8s*)(sW2a + (ct * 16 + m) * 72 + q * 8), acc);
            acc = MFMA16(a21, *(const v8s*)(sW2a + (ct * 16 + m) * 72 + 32 + q * 8), acc);
            #pragma unroll
            for (int r = 0; r < 4; ++r)
                zb[(q * 4 + r) * PZ + ((ct * 16 + m) ^ (q << 4))] = bf16r(fmaxf(acc[r], 0.f));
        }
    }

    // ---- layer 2b: 64 -> 64, relu ---------------------------------------
    {
        const v8s a20 = *(const v8s*)(zb + m * PZ + ((q * 8) ^ SWL(m)));
        const v8s a21 = *(const v8s*)(zb + m * PZ + ((32 + q * 8) ^ SWL(m)));
        #pragma unroll
        for (int ct = 0; ct < 4; ++ct) {
            const float bv = bb2b[ct];
            v4f acc = {bv, bv, bv, bv};
            acc = MFMA16(a20, *(const v8s*)(sW2b + (ct * 16 + m) * 72 + q * 8), acc);
            acc = MFMA16(a21, *(const v8s*)(sW2b + (ct * 16 + m) * 72 + 32 + q * 8), acc);
            #pragma unroll
            for (int r = 0; r < 4; ++r)
                zb[(q * 4 + r) * PZ + ((ct * 16 + m) ^ (q << 4))] = bf16r(fmaxf(acc[r], 0.f));
        }
    }

    // ---- layer 2c: 64 -> 3, sigmoid, scatter store ----------------------
    {
        const v8s a30 = *(const v8s*)(zb + m * PZ + ((q * 8) ^ SWL(m)));
        const v8s a31 = *(const v8s*)(zb + m * PZ + ((32 + q * 8) ^ SWL(m)));
        v4f cacc = {bb2c, bb2c, bb2c, bb2c};
        cacc = MFMA16(a30, *(const v8s*)(sW2c + m * 72 + q * 8), cacc);
        cacc = MFMA16(a31, *(const v8s*)(sW2c + m * 72 + 32 + q * 8), cacc);

        if (m < 3) {
            #pragma unroll
            for (int r = 0; r < 4; ++r) {
                const unsigned pj = idxbuf[j0 + q * 4 + r];
                if (pj < (unsigned)NPTS) {
                    const float cv = 1.0f / (1.0f + __expf(-cacc[r]));
                    out[3 * pj + m] = cv;
                }
            }
        }
        if (m == 0) {
            #pragma unroll
            for (int r = 0; r < 4; ++r) {
                const unsigned pj = idxbuf[j0 + q * 4 + r];
                if (pj < (unsigned)NPTS)
                    out[3 * NPTS + pj] = __expf(hacc[r]);
            }
        }
    }
}

// ---------------- fallback: fused VALU kernel (if ws too small) -------------
__global__ __launch_bounds__(256) void ngp_fused(
    const float* __restrict__ x, const float* __restrict__ d,
    const float* __restrict__ tables,
    const float* __restrict__ w1a, const float* __restrict__ b1a,
    const float* __restrict__ w1b, const float* __restrict__ b1b,
    const float* __restrict__ w2a, const float* __restrict__ b2a,
    const float* __restrict__ w2b, const float* __restrict__ b2b,
    const float* __restrict__ w2c, const float* __restrict__ b2c,
    float* __restrict__ out)
{
    const int i = blockIdx.x * 256 + threadIdx.x;
    if (i >= NPTS) return;
    const float xs0 = x[3*i+0] / 3.0f;
    const float xs1 = x[3*i+1] / 3.0f;
    const float xs2 = x[3*i+2] / 3.0f;
    const bool mask = (fabsf(xs0) < 0.5f) & (fabsf(xs1) < 0.5f) & (fabsf(xs2) < 0.5f);
    const float xu0 = xs0 + 0.5f, xu1 = xs1 + 0.5f, xu2 = xs2 + 0.5f;

    float feats[32];
    #pragma unroll
    for (int l = 0; l < 16; ++l) {
        const float n = NLf[l];
        const float p0 = xu0 * n, p1 = xu1 * n, p2 = xu2 * n;
        const float f0 = floorf(p0), f1 = floorf(p1), f2 = floorf(p2);
        const float fr0 = p0 - f0, fr1 = p1 - f1, fr2 = p2 - f2;
        const int vf0 = (int)f0, vf1 = (int)f1, vf2 = (int)f2;
        const int vc0 = (int)ceilf(p0), vc1 = (int)ceilf(p1), vc2 = (int)ceilf(p2);
        const float2* tbl = (const float2*)(tables + (size_t)l * (TSZ * 2));
        float a0 = 0.f, a1 = 0.f;
        #pragma unroll
        for (int k = 0; k < 8; ++k) {
            const unsigned vx = (unsigned)(((CEILX >> k) & 1) ? vc0 : vf0);
            const unsigned vy = (unsigned)(((CEILY >> k) & 1) ? vc1 : vf1);
            const unsigned vz = (unsigned)(((CEILZ >> k) & 1) ? vc2 : vf2);
            const unsigned h = (vx ^ (vy * 2654435761u) ^ (vz * 805459861u)) & TMASK;
            const float wx = (k & 1)        ? fr0 : 1.0f - fr0;
            const float wy = ((k >> 1) & 1) ? fr1 : 1.0f - fr1;
            const float wz = ((k >> 2) & 1) ? fr2 : 1.0f - fr2;
            const float wgt = wx * wy * wz;
            const float2 t = tbl[h];
            a0 = fmaf(wgt, t.x, a0);
            a1 = fmaf(wgt, t.y, a1);
        }
        feats[2*l] = a0; feats[2*l+1] = a1;
    }

    float h2v[16];
    #pragma unroll
    for (int j = 0; j < 16; ++j) h2v[j] = b1b[j];
    #pragma unroll
    for (int c = 0; c < 4; ++c) {
        float h1c[16];
        #pragma unroll
        for (int jj = 0; jj < 16; ++jj) h1c[jj] = b1a[16*c + jj];
        #pragma unroll
        for (int i2 = 0; i2 < 32; ++i2) {
            const float f = feats[i2];
            #pragma unroll
            for (int jj = 0; jj < 16; ++jj)
                h1c[jj] = fmaf(f, w1a[i2*64 + 16*c + jj], h1c[jj]);
        }
        #pragma unroll
        for (int jj = 0; jj < 16; ++jj) {
            const float f = fmaxf(h1c[jj], 0.f);
            #pragma unroll
            for (int t = 0; t < 16; ++t)
                h2v[t] = fmaf(f, w1b[(16*c + jj)*16 + t], h2v[t]);
        }
    }

    float z1[64];
    #pragma unroll
    for (int j = 0; j < 64; ++j) z1[j] = b2a[j];
    #pragma unroll
    for (int i2 = 0; i2 < 16; ++i2) {
        const float f = h2v[i2];
        #pragma unroll
        for (int j = 0; j < 64; ++j) z1[j] = fmaf(f, w2a[i2*64 + j], z1[j]);
    }
    const float d0 = d[3*i+0], d1 = d[3*i+1], d2 = d[3*i+2];
    {
        const float* r = w2a + 16*64;
        #pragma unroll
        for (int j = 0; j < 64; ++j) z1[j] = fmaf(d0, r[j], z1[j]);
        r = w2a + 17*64;
        #pragma unroll
        for (int j = 0; j < 64; ++j) z1[j] = fmaf(d1, r[j], z1[j]);
        r = w2a + 18*64;
        #pragma unroll
        for (int j = 0; j < 64; ++j) z1[j] = fmaf(d2, r[j], z1[j]);
    }
    #pragma unroll
    for (int e = 0; e < 4; ++e) {
        const float mm = (float)(1 << e);
        const float dv[3] = {d0, d1, d2};
        #pragma unroll
        for (int a = 0; a < 3; ++a) {
            const float sv = __sinf(mm * dv[a]);
            const float* rs = w2a + (19 + 6*e + a)*64;
            #pragma unroll
            for (int j = 0; j < 64; ++j) z1[j] = fmaf(sv, rs[j], z1[j]);
        }
        #pragma unroll
        for (int a = 0; a < 3; ++a) {
            const float cv = __cosf(mm * dv[a]);
            const float* rc = w2a + (19 + 6*e + 3 + a)*64;
            #pragma unroll
            for (int j = 0; j < 64; ++j) z1[j] = fmaf(cv, rc[j], z1[j]);
        }
    }
    #pragma unroll
    for (int j = 0; j < 64; ++j) z1[j] = fmaxf(z1[j], 0.f);

    float ca = b2c[0], cb = b2c[1], cc = b2c[2];
    #pragma unroll
    for (int jc = 0; jc < 64; jc += 16) {
        float acc[16];
        #pragma unroll
        for (int jj = 0; jj < 16; ++jj) acc[jj] = b2b[jc + jj];
        #pragma unroll
        for (int i2 = 0; i2 < 64; ++i2) {
            const float f = z1[i2];
            #pragma unroll
            for (int jj = 0; jj < 16; ++jj)
                acc[jj] = fmaf(f, w2b[i2*64 + jc + jj], acc[jj]);
        }
        #pragma unroll
        for (int jj = 0; jj < 16; ++jj) {
            const float v = fmaxf(acc[jj], 0.f);
            ca = fmaf(v, w2c[(jc + jj)*3 + 0], ca);
            cb = fmaf(v, w2c[(jc + jj)*3 + 1], cb);
            cc = fmaf(v, w2c[(jc + jj)*3 + 2], cc);
        }
    }

    float r = 1.0f / (1.0f + __expf(-ca));
    float g = 1.0f / (1.0f + __expf(-cb));
    float b = 1.0f / (1.0f + __expf(-cc));
    float sigma;
    if (mask) { sigma = __expf(h2v[0]); }
    else { r = 0.f; g = 0.f; b = 0.f; sigma = 0.f; }
    out[3*i + 0] = r;
    out[3*i + 1] = g;
    out[3*i + 2] = b;
    out[3*NPTS + i] = sigma;
}

extern "C" void kernel_launch(void* const* d_in, const int* in_sizes, int n_in,
                              void* d_out, int out_size, void* d_ws, size_t ws_size,
                              hipStream_t stream) {
    const float* x      = (const float*)d_in[0];
    const float* d      = (const float*)d_in[1];
    const float* tables = (const float*)d_in[2];
    const float* w1a    = (const float*)d_in[3];
    const float* b1a    = (const float*)d_in[4];
    const float* w1b    = (const float*)d_in[5];
    const float* b1b    = (const float*)d_in[6];
    const float* w2a    = (const float*)d_in[7];
    const float* b2a    = (const float*)d_in[8];
    const float* w2b    = (const float*)d_in[9];
    const float* b2b    = (const float*)d_in[10];
    const float* w2c    = (const float*)d_in[11];
    const float* b2c    = (const float*)d_in[12];
    float* out = (float*)d_out;

    // ws layout (u32 units): [0,16N) feats_pk; [16N,32N) tables_pk;
    // [32N,33N) idxbuf; [33N] counter; [34N, 37N) xc (float3, compacted)
    const size_t need = (size_t)37 * NPTS * 4;   // ~74 MiB
    if (ws_size >= need) {
        unsigned* base      = (unsigned*)d_ws;
        unsigned* feats_pk  = base;
        unsigned* tables_pk = base + (size_t)16 * NPTS;
        unsigned* idxbuf    = base + (size_t)32 * NPTS;
        unsigned* cnt       = base + (size_t)33 * NPTS;
        float*    xc        = (float*)(base + (size_t)34 * NPTS);

        dim3 gp(16 * TSZ / (256 * 2)), bp(256);
        hipLaunchKernelGGL(pack_tables, gp, bp, 0, stream,
                           (const float4*)tables, (uint2*)tables_pk, idxbuf, cnt);

        dim3 gc(NPTS / 256), bc(256);
        hipLaunchKernelGGL(ngp_compact, gc, bc, 0, stream, x, idxbuf, xc, cnt, out);

        dim3 gh(NPTS / 256, 16), bh(256);
        hipLaunchKernelGGL(ngp_hash5, gh, bh, 0, stream, xc, tables_pk, cnt, feats_pk);

        dim3 gm(NPTS / 128), bm(512);
        hipLaunchKernelGGL(ngp_mlp4, gm, bm, 0, stream,
                           d, feats_pk, idxbuf, cnt, w1a, b1a, w1b, b1b,
                           w2a, b2a, w2b, b2b, w2c, b2c, out);
    } else {
        dim3 grid(NPTS / 256), block(256);
        hipLaunchKernelGGL(ngp_fused, grid, block, 0, stream,
                           x, d, tables, w1a, b1a, w1b, b1b,
                           w2a, b2a, w2b, b2b, w2c, b2c, out);
    }
}

// Round 5
// 289.881 us; speedup vs baseline: 1.2910x; 1.2910x over previous
//
#include <hip/hip_runtime.h>
#include <math.h>

#define NPTS 524288
#define HALF (NPTS / 2)
#define TSZ  524288
#define TMASK (TSZ - 1)

typedef __attribute__((ext_vector_type(8))) short v8s;   // 8 x bf16 (4 VGPR)
typedef __attribute__((ext_vector_type(4))) float v4f;   // MFMA C/D frag

#define MFMA16(a, b, c) __builtin_amdgcn_mfma_f32_16x16x32_bf16(a, b, c, 0, 0, 0)

__device__ __constant__ float NLf[16] = {
    16.f, 22.f, 30.f, 42.f, 58.f, 80.f, 110.f, 152.f,
    209.f, 288.f, 397.f, 547.f, 754.f, 1039.f, 1432.f, 1974.f
};

#define CEILX 0xE2
#define CEILY 0xD4
#define CEILZ 0xB8

__device__ __forceinline__ short bf16r(float v) {  // f32 -> bf16 RNE
    unsigned b = __float_as_uint(v);
    b += 0x7FFFu + ((b >> 16) & 1u);
    return (short)(b >> 16);
}
__device__ __forceinline__ unsigned packbf(float a, float b) {
    return (unsigned)(unsigned short)bf16r(a) | ((unsigned)(unsigned short)bf16r(b) << 16);
}
__device__ __forceinline__ unsigned sel4(uint4 t, unsigned i) {
    const unsigned ab = (i & 1u) ? t.y : t.x;
    const unsigned cd = (i & 1u) ? t.w : t.z;
    return (i & 2u) ? cd : ab;
}

// ---- kernel 0: pack fp32 tables -> bf16x2; init idx sentinel + counter -----
__global__ __launch_bounds__(256) void pack_tables(
    const float4* __restrict__ tbl, uint2* __restrict__ out,
    unsigned* __restrict__ idxbuf, unsigned* __restrict__ cnt)
{
    const int idx = blockIdx.x * 256 + threadIdx.x;   // handles 2 entries
    const float4 t = tbl[idx];
    out[idx] = make_uint2(packbf(t.x, t.y), packbf(t.z, t.w));
    if (idx < NPTS) idxbuf[idx] = 0xFFFFFFFFu;        // sentinel for tail tiles
    if (idx == 0) cnt[0] = 0u;
}

// ---- kernel 0b: mask + stream compaction (block-aggregated atomic) ---------
// R4 post-mortem: 8192 same-address wave-atomics ~= 65us serial. Now ONE
// atomicAdd per 1024-thread block (512 total). Also emits compacted d (dc)
// so the MLP posenc reads contiguously instead of gathering through idx.
__global__ __launch_bounds__(1024) void ngp_compact2(
    const float* __restrict__ x, const float* __restrict__ d,
    unsigned* __restrict__ idxbuf, float* __restrict__ xc,
    float* __restrict__ dc, unsigned* __restrict__ cnt,
    float* __restrict__ out)
{
    __shared__ unsigned sWCnt[16];
    __shared__ unsigned sBase;

    const int tid  = threadIdx.x;
    const int wv   = tid >> 6, lane = tid & 63;
    const int i    = blockIdx.x * 1024 + tid;

    const float x0 = x[3*i+0], x1 = x[3*i+1], x2 = x[3*i+2];
    const float xs0 = x0 / 3.0f, xs1 = x1 / 3.0f, xs2 = x2 / 3.0f;
    const bool act = (fabsf(xs0) < 0.5f) && (fabsf(xs1) < 0.5f) && (fabsf(xs2) < 0.5f);
    if (!act) {
        out[3*i+0] = 0.f; out[3*i+1] = 0.f; out[3*i+2] = 0.f;
        out[3*NPTS + i] = 0.f;
    }
    const unsigned long long mb = __ballot(act);
    if (lane == 0) sWCnt[wv] = (unsigned)__popcll(mb);
    __syncthreads();
    if (tid == 0) {
        unsigned tot = 0;
        #pragma unroll
        for (int w = 0; w < 16; ++w) tot += sWCnt[w];
        sBase = atomicAdd(cnt, tot);
    }
    __syncthreads();
    if (act) {
        unsigned off = sBase;
        for (int w = 0; w < wv; ++w) off += sWCnt[w];
        off += (unsigned)__popcll(mb & ((1ull << lane) - 1ull));
        idxbuf[off] = (unsigned)i;
        xc[3*off+0] = x0; xc[3*off+1] = x1; xc[3*off+2] = x2;
        dc[3*off+0] = d[3*i+0]; dc[3*off+1] = d[3*i+1]; dc[3*off+2] = d[3*i+2];
    }
}

// ---- kernel 1: hash gather on compacted points (R4 verified: 107us) --------
__global__ __launch_bounds__(256) void ngp_hash5(
    const float* __restrict__ xc, const unsigned* __restrict__ tables_pk,
    const unsigned* __restrict__ cnt, unsigned* __restrict__ feats_pk)
{
    __shared__ float sX[768];
    const int NC = (int)cnt[0];
    if (blockIdx.x * 256 >= NC) return;       // compacted tail: nothing to do

    const int tid = threadIdx.x;
    const int l = blockIdx.y;
    const float n = NLf[l];
    const unsigned* tbl = tables_pk + (size_t)l * TSZ;

    for (int r = tid; r < 768; r += 256)
        sX[r] = xc[(size_t)blockIdx.x * 768 + r];
    __syncthreads();

    const int j = blockIdx.x * 256 + tid;     // compact index (>=NC rows: unused)
    const float xu0 = sX[tid * 3 + 0] / 3.0f + 0.5f;
    const float xu1 = sX[tid * 3 + 1] / 3.0f + 0.5f;
    const float xu2 = sX[tid * 3 + 2] / 3.0f + 0.5f;

    const float p0 = xu0 * n, p1 = xu1 * n, p2 = xu2 * n;
    const float f0 = floorf(p0), f1 = floorf(p1), f2 = floorf(p2);
    const float fr0 = p0 - f0, fr1 = p1 - f1, fr2 = p2 - f2;
    const float g0 = 1.f - fr0, g1 = 1.f - fr1, g2 = 1.f - fr2;
    const unsigned uvf0 = (unsigned)(int)f0;
    const unsigned uvc0 = (unsigned)(int)ceilf(p0);
    const unsigned syf = (unsigned)(int)f1 * 2654435761u;
    const unsigned syc = (unsigned)(int)ceilf(p1) * 2654435761u;
    const unsigned szf = (unsigned)(int)f2 * 805459861u;
    const unsigned szc = (unsigned)(int)ceilf(p2) * 805459861u;

    const float w0 = g0 * g1 * g2,  w1 = fr0 * g1 * g2;
    const float w2 = g0 * fr1 * g2, w6 = g0 * fr1 * fr2;
    const float w3 = fr0 * fr1 * g2, w5 = fr0 * g1 * fr2;
    const float w4 = g0 * g1 * fr2, w7 = fr0 * fr1 * fr2;

    const unsigned Ss[4] = { syf ^ szf, syc ^ szf, syf ^ szc, syc ^ szc };
    const float wf[4] = { w0, w2, w3, w4 };
    const float wc[4] = { w1, w6, w5, w7 };

    float a0 = 0.f, a1 = 0.f;
    #pragma unroll
    for (int pr = 0; pr < 4; ++pr) {
        const unsigned hf = (Ss[pr] ^ uvf0) & TMASK;
        const unsigned hc = (Ss[pr] ^ uvc0) & TMASK;
        const unsigned diff = hf ^ hc;
        const uint4 tv = *(const uint4*)(tbl + (hf & ~3u));
        const unsigned ef = sel4(tv, hf & 3u);
        unsigned ec;
        if (diff <= 3u) ec = sel4(tv, hc & 3u);
        else            ec = tbl[hc];
        a0 = fmaf(wf[pr], __uint_as_float(ef << 16), a0);
        a1 = fmaf(wf[pr], __uint_as_float(ef & 0xFFFF0000u), a1);
        a0 = fmaf(wc[pr], __uint_as_float(ec << 16), a0);
        a1 = fmaf(wc[pr], __uint_as_float(ec & 0xFFFF0000u), a1);
    }
    feats_pk[(size_t)l * NPTS + j] = packbf(a0, a1);
}

// ---- kernel 2: MFMA MLP on compacted points (dc contiguous posenc) ---------
#define PZ 72   // z-buffer pitch in shorts (144 B, 16B-aligned)
#define SWL(row) ((((row) >> 2) & 3) << 4)

__global__ __launch_bounds__(512) void ngp_mlp5(
    const float* __restrict__ dc,
    const unsigned* __restrict__ feats_pk, const unsigned* __restrict__ idxbuf,
    const unsigned* __restrict__ cnt,
    const float* __restrict__ w1a, const float* __restrict__ b1a,
    const float* __restrict__ w1b, const float* __restrict__ b1b,
    const float* __restrict__ w2a, const float* __restrict__ b2a,
    const float* __restrict__ w2b, const float* __restrict__ b2b,
    const float* __restrict__ w2c, const float* __restrict__ b2c,
    float* __restrict__ out)
{
    __shared__ short sW1a[64 * 40];
    __shared__ short sW1b[16 * 72];
    __shared__ short sW2a[64 * 72];
    __shared__ short sW2b[64 * 72];
    __shared__ short sW2c[16 * 72];
    __shared__ short sZ[8 * 16 * PZ];

    const int NC = (int)cnt[0];
    if (blockIdx.x * 128 >= NC) return;       // whole block beyond compact set

    const int tid = threadIdx.x;

    for (int idx = tid; idx < 32 * 64; idx += 512) {
        const int k = idx >> 6, n2 = idx & 63;
        sW1a[n2 * 40 + k] = bf16r(w1a[k * 64 + n2]);
    }
    for (int idx = tid; idx < 64 * 16; idx += 512) {
        const int k = idx >> 4, n2 = idx & 15;
        sW1b[n2 * 72 + k] = bf16r(w1b[k * 16 + n2]);
    }
    for (int idx = tid; idx < 64 * 64; idx += 512) {
        const int k = idx >> 6, n2 = idx & 63;
        sW2a[n2 * 72 + k] = bf16r(k < 43 ? w2a[k * 64 + n2] : 0.f);
    }
    for (int idx = tid; idx < 64 * 64; idx += 512) {
        const int k = idx >> 6, n2 = idx & 63;
        sW2b[n2 * 72 + k] = bf16r(w2b[k * 64 + n2]);
    }
    for (int idx = tid; idx < 64 * 16; idx += 512) {
        const int k = idx >> 4, n2 = idx & 15;
        sW2c[n2 * 72 + k] = bf16r(n2 < 3 ? w2c[k * 3 + n2] : 0.f);
    }
    __syncthreads();

    const int wave = tid >> 6, lane = tid & 63;
    const int m = lane & 15, q = lane >> 4;
    short* zb = &sZ[wave * 16 * PZ];

    const int j0 = (blockIdx.x * 8 + wave) * 16;   // this wave's compact tile
    if (j0 >= NC) return;                          // after staging+sync: safe

    float bb1a[4], bb2a[4], bb2b[4];
    #pragma unroll
    for (int ct = 0; ct < 4; ++ct) {
        bb1a[ct] = b1a[ct * 16 + m];
        bb2a[ct] = b2a[ct * 16 + m];
        bb2b[ct] = b2b[ct * 16 + m];
    }
    const float bb1b = b1b[m];
    const float bb2c = (m < 3) ? b2c[m] : 0.f;

    // ---- feats -> z cols [0,32), swizzled ------------------------------
    #pragma unroll
    for (int it = 0; it < 4; ++it) {
        const int l = it * 4 + q;
        *(unsigned*)(zb + m * PZ + ((2 * l) ^ SWL(m))) =
            feats_pk[(size_t)l * NPTS + j0 + m];
    }

    // ---- layer 1a: feats(32) -> 64, relu --------------------------------
    {
        const v8s a0 = *(const v8s*)(zb + m * PZ + ((q * 8) ^ SWL(m)));
        #pragma unroll
        for (int ct = 0; ct < 4; ++ct) {
            const float bv = bb1a[ct];
            v4f acc = {bv, bv, bv, bv};
            acc = MFMA16(a0, *(const v8s*)(sW1a + (ct * 16 + m) * 40 + q * 8), acc);
            #pragma unroll
            for (int r = 0; r < 4; ++r)
                zb[(q * 4 + r) * PZ + ((ct * 16 + m) ^ (q << 4))] = bf16r(fmaxf(acc[r], 0.f));
        }
    }

    // ---- layer 1b: 64 -> 16 (h; h[0] is log_sigma) ----------------------
    v4f hacc;
    {
        const v8s a10 = *(const v8s*)(zb + m * PZ + ((q * 8) ^ SWL(m)));
        const v8s a11 = *(const v8s*)(zb + m * PZ + ((32 + q * 8) ^ SWL(m)));
        v4f hv = {bb1b, bb1b, bb1b, bb1b};
        hv = MFMA16(a10, *(const v8s*)(sW1b + m * 72 + q * 8), hv);
        hv = MFMA16(a11, *(const v8s*)(sW1b + m * 72 + 32 + q * 8), hv);
        hacc = hv;
        #pragma unroll
        for (int r = 0; r < 4; ++r)
            zb[(q * 4 + r) * PZ + (m ^ (q << 4))] = bf16r(hv[r]);
    }

    // ---- posenc(dc) into z cols [16,43), zero pad [48,64) ---------------
    {
        const float dd0 = dc[3*(j0+m)+0], dd1 = dc[3*(j0+m)+1], dd2 = dc[3*(j0+m)+2];
        v8s pk;
        #pragma unroll
        for (int jj = 0; jj < 8; ++jj) {
            const int k = 16 + q * 8 + jj;
            float v;
            if (k < 19) {
                v = (k == 16) ? dd0 : ((k == 17) ? dd1 : dd2);
            } else if (k < 43) {
                const int idx = k - 19;
                const int e = idx / 6, w = idx - 6 * e;
                const float base = (w == 0 || w == 3) ? dd0 : ((w == 1 || w == 4) ? dd1 : dd2);
                const float s = (float)(1 << e) * base;
                v = (w < 3) ? __sinf(s) : __cosf(s);
            } else {
                v = 0.f;
            }
            pk[jj] = bf16r(v);
        }
        *(v8s*)(zb + m * PZ + ((16 + q * 8) ^ SWL(m))) = pk;
        *(unsigned long long*)(zb + m * PZ + ((48 + q * 4) ^ SWL(m))) = 0ull;
    }

    // ---- layer 2a: z(43,pad64) -> 64, relu ------------------------------
    {
        const v8s a20 = *(const v8s*)(zb + m * PZ + ((q * 8) ^ SWL(m)));
        const v8s a21 = *(const v8s*)(zb + m * PZ + ((32 + q * 8) ^ SWL(m)));
        #pragma unroll
        for (int ct = 0; ct < 4; ++ct) {
            const float bv = bb2a[ct];
            v4f acc = {bv, bv, bv, bv};
            acc = MFMA16(a20, *(const v8s*)(sW2a + (ct * 16 + m) * 72 + q * 8), acc);
            acc = MFMA16(a21, *(const v8s*)(sW2a + (ct * 16 + m) * 72 + 32 + q * 8), acc);
            #pragma unroll
            for (int r = 0; r < 4; ++r)
                zb[(q * 4 + r) * PZ + ((ct * 16 + m) ^ (q << 4))] = bf16r(fmaxf(acc[r], 0.f));
        }
    }

    // ---- layer 2b: 64 -> 64, relu ---------------------------------------
    {
        const v8s a20 = *(const v8s*)(zb + m * PZ + ((q * 8) ^ SWL(m)));
        const v8s a21 = *(const v8s*)(zb + m * PZ + ((32 + q * 8) ^ SWL(m)));
        #pragma unroll
        for (int ct = 0; ct < 4; ++ct) {
            const float bv = bb2b[ct];
            v4f acc = {bv, bv, bv, bv};
            acc = MFMA16(a20, *(const v8s*)(sW2b + (ct * 16 + m) * 72 + q * 8), acc);
            acc = MFMA16(a21, *(const v8s*)(sW2b + (ct * 16 + m) * 72 + 32 + q * 8), acc);
            #pragma unroll
            for (int r = 0; r < 4; ++r)
                zb[(q * 4 + r) * PZ + ((ct * 16 + m) ^ (q << 4))] = bf16r(fmaxf(acc[r], 0.f));
        }
    }

    // ---- layer 2c: 64 -> 3, sigmoid, scatter store ----------------------
    {
        const v8s a30 = *(const v8s*)(zb + m * PZ + ((q * 8) ^ SWL(m)));
        const v8s a31 = *(const v8s*)(zb + m * PZ + ((32 + q * 8) ^ SWL(m)));
        v4f cacc = {bb2c, bb2c, bb2c, bb2c};
        cacc = MFMA16(a30, *(const v8s*)(sW2c + m * 72 + q * 8), cacc);
        cacc = MFMA16(a31, *(const v8s*)(sW2c + m * 72 + 32 + q * 8), cacc);

        if (m < 3) {
            #pragma unroll
            for (int r = 0; r < 4; ++r) {
                const unsigned pj = idxbuf[j0 + q * 4 + r];
                if (pj < (unsigned)NPTS) {
                    const float cv = 1.0f / (1.0f + __expf(-cacc[r]));
                    out[3 * pj + m] = cv;
                }
            }
        }
        if (m == 0) {
            #pragma unroll
            for (int r = 0; r < 4; ++r) {
                const unsigned pj = idxbuf[j0 + q * 4 + r];
                if (pj < (unsigned)NPTS)
                    out[3 * NPTS + pj] = __expf(hacc[r]);
            }
        }
    }
}

// ---------------- fallback: fused VALU kernel (if ws too small) -------------
__global__ __launch_bounds__(256) void ngp_fused(
    const float* __restrict__ x, const float* __restrict__ d,
    const float* __restrict__ tables,
    const float* __restrict__ w1a, const float* __restrict__ b1a,
    const float* __restrict__ w1b, const float* __restrict__ b1b,
    const float* __restrict__ w2a, const float* __restrict__ b2a,
    const float* __restrict__ w2b, const float* __restrict__ b2b,
    const float* __restrict__ w2c, const float* __restrict__ b2c,
    float* __restrict__ out)
{
    const int i = blockIdx.x * 256 + threadIdx.x;
    if (i >= NPTS) return;
    const float xs0 = x[3*i+0] / 3.0f;
    const float xs1 = x[3*i+1] / 3.0f;
    const float xs2 = x[3*i+2] / 3.0f;
    const bool mask = (fabsf(xs0) < 0.5f) & (fabsf(xs1) < 0.5f) & (fabsf(xs2) < 0.5f);
    const float xu0 = xs0 + 0.5f, xu1 = xs1 + 0.5f, xu2 = xs2 + 0.5f;

    float feats[32];
    #pragma unroll
    for (int l = 0; l < 16; ++l) {
        const float n = NLf[l];
        const float p0 = xu0 * n, p1 = xu1 * n, p2 = xu2 * n;
        const float f0 = floorf(p0), f1 = floorf(p1), f2 = floorf(p2);
        const float fr0 = p0 - f0, fr1 = p1 - f1, fr2 = p2 - f2;
        const int vf0 = (int)f0, vf1 = (int)f1, vf2 = (int)f2;
        const int vc0 = (int)ceilf(p0), vc1 = (int)ceilf(p1), vc2 = (int)ceilf(p2);
        const float2* tbl = (const float2*)(tables + (size_t)l * (TSZ * 2));
        float a0 = 0.f, a1 = 0.f;
        #pragma unroll
        for (int k = 0; k < 8; ++k) {
            const unsigned vx = (unsigned)(((CEILX >> k) & 1) ? vc0 : vf0);
            const unsigned vy = (unsigned)(((CEILY >> k) & 1) ? vc1 : vf1);
            const unsigned vz = (unsigned)(((CEILZ >> k) & 1) ? vc2 : vf2);
            const unsigned h = (vx ^ (vy * 2654435761u) ^ (vz * 805459861u)) & TMASK;
            const float wx = (k & 1)        ? fr0 : 1.0f - fr0;
            const float wy = ((k >> 1) & 1) ? fr1 : 1.0f - fr1;
            const float wz = ((k >> 2) & 1) ? fr2 : 1.0f - fr2;
            const float wgt = wx * wy * wz;
            const float2 t = tbl[h];
            a0 = fmaf(wgt, t.x, a0);
            a1 = fmaf(wgt, t.y, a1);
        }
        feats[2*l] = a0; feats[2*l+1] = a1;
    }

    float h2v[16];
    #pragma unroll
    for (int j = 0; j < 16; ++j) h2v[j] = b1b[j];
    #pragma unroll
    for (int c = 0; c < 4; ++c) {
        float h1c[16];
        #pragma unroll
        for (int jj = 0; jj < 16; ++jj) h1c[jj] = b1a[16*c + jj];
        #pragma unroll
        for (int i2 = 0; i2 < 32; ++i2) {
            const float f = feats[i2];
            #pragma unroll
            for (int jj = 0; jj < 16; ++jj)
                h1c[jj] = fmaf(f, w1a[i2*64 + 16*c + jj], h1c[jj]);
        }
        #pragma unroll
        for (int jj = 0; jj < 16; ++jj) {
            const float f = fmaxf(h1c[jj], 0.f);
            #pragma unroll
            for (int t = 0; t < 16; ++t)
                h2v[t] = fmaf(f, w1b[(16*c + jj)*16 + t], h2v[t]);
        }
    }

    float z1[64];
    #pragma unroll
    for (int j = 0; j < 64; ++j) z1[j] = b2a[j];
    #pragma unroll
    for (int i2 = 0; i2 < 16; ++i2) {
        const float f = h2v[i2];
        #pragma unroll
        for (int j = 0; j < 64; ++j) z1[j] = fmaf(f, w2a[i2*64 + j], z1[j]);
    }
    const float d0 = d[3*i+0], d1 = d[3*i+1], d2 = d[3*i+2];
    {
        const float* r = w2a + 16*64;
        #pragma unroll
        for (int j = 0; j < 64; ++j) z1[j] = fmaf(d0, r[j], z1[j]);
        r = w2a + 17*64;
        #pragma unroll
        for (int j = 0; j < 64; ++j) z1[j] = fmaf(d1, r[j], z1[j]);
        r = w2a + 18*64;
        #pragma unroll
        for (int j = 0; j < 64; ++j) z1[j] = fmaf(d2, r[j], z1[j]);
    }
    #pragma unroll
    for (int e = 0; e < 4; ++e) {
        const float mm = (float)(1 << e);
        const float dv[3] = {d0, d1, d2};
        #pragma unroll
        for (int a = 0; a < 3; ++a) {
            const float sv = __sinf(mm * dv[a]);
            const float* rs = w2a + (19 + 6*e + a)*64;
            #pragma unroll
            for (int j = 0; j < 64; ++j) z1[j] = fmaf(sv, rs[j], z1[j]);
        }
        #pragma unroll
        for (int a = 0; a < 3; ++a) {
            const float cv = __cosf(mm * dv[a]);
            const float* rc = w2a + (19 + 6*e + 3 + a)*64;
            #pragma unroll
            for (int j = 0; j < 64; ++j) z1[j] = fmaf(cv, rc[j], z1[j]);
        }
    }
    #pragma unroll
    for (int j = 0; j < 64; ++j) z1[j] = fmaxf(z1[j], 0.f);

    float ca = b2c[0], cb = b2c[1], cc = b2c[2];
    #pragma unroll
    for (int jc = 0; jc < 64; jc += 16) {
        float acc[16];
        #pragma unroll
        for (int jj = 0; jj < 16; ++jj) acc[jj] = b2b[jc + jj];
        #pragma unroll
        for (int i2 = 0; i2 < 64; ++i2) {
            const float f = z1[i2];
            #pragma unroll
            for (int jj = 0; jj < 16; ++jj)
                acc[jj] = fmaf(f, w2b[i2*64 + jc + jj], acc[jj]);
        }
        #pragma unroll
        for (int jj = 0; jj < 16; ++jj) {
            const float v = fmaxf(acc[jj], 0.f);
            ca = fmaf(v, w2c[(jc + jj)*3 + 0], ca);
            cb = fmaf(v, w2c[(jc + jj)*3 + 1], cb);
            cc = fmaf(v, w2c[(jc + jj)*3 + 2], cc);
        }
    }

    float r = 1.0f / (1.0f + __expf(-ca));
    float g = 1.0f / (1.0f + __expf(-cb));
    float b = 1.0f / (1.0f + __expf(-cc));
    float sigma;
    if (mask) { sigma = __expf(h2v[0]); }
    else { r = 0.f; g = 0.f; b = 0.f; sigma = 0.f; }
    out[3*i + 0] = r;
    out[3*i + 1] = g;
    out[3*i + 2] = b;
    out[3*NPTS + i] = sigma;
}

extern "C" void kernel_launch(void* const* d_in, const int* in_sizes, int n_in,
                              void* d_out, int out_size, void* d_ws, size_t ws_size,
                              hipStream_t stream) {
    const float* x      = (const float*)d_in[0];
    const float* d      = (const float*)d_in[1];
    const float* tables = (const float*)d_in[2];
    const float* w1a    = (const float*)d_in[3];
    const float* b1a    = (const float*)d_in[4];
    const float* w1b    = (const float*)d_in[5];
    const float* b1b    = (const float*)d_in[6];
    const float* w2a    = (const float*)d_in[7];
    const float* b2a    = (const float*)d_in[8];
    const float* w2b    = (const float*)d_in[9];
    const float* b2b    = (const float*)d_in[10];
    const float* w2c    = (const float*)d_in[11];
    const float* b2c    = (const float*)d_in[12];
    float* out = (float*)d_out;

    // ws layout (u32 units): [0,16N) feats_pk; [16N,32N) tables_pk;
    // [32N,33N) idxbuf; [33N] counter; [34N,37N) xc; [37N,40N) dc
    const size_t need = (size_t)40 * NPTS * 4;   // ~80 MiB
    if (ws_size >= need) {
        unsigned* base      = (unsigned*)d_ws;
        unsigned* feats_pk  = base;
        unsigned* tables_pk = base + (size_t)16 * NPTS;
        unsigned* idxbuf    = base + (size_t)32 * NPTS;
        unsigned* cnt       = base + (size_t)33 * NPTS;
        float*    xc        = (float*)(base + (size_t)34 * NPTS);
        float*    dc        = (float*)(base + (size_t)37 * NPTS);

        dim3 gp(16 * TSZ / (256 * 2)), bp(256);
        hipLaunchKernelGGL(pack_tables, gp, bp, 0, stream,
                           (const float4*)tables, (uint2*)tables_pk, idxbuf, cnt);

        dim3 gc(NPTS / 1024), bc(1024);
        hipLaunchKernelGGL(ngp_compact2, gc, bc, 0, stream,
                           x, d, idxbuf, xc, dc, cnt, out);

        dim3 gh(NPTS / 256, 16), bh(256);
        hipLaunchKernelGGL(ngp_hash5, gh, bh, 0, stream, xc, tables_pk, cnt, feats_pk);

        dim3 gm(NPTS / 128), bm(512);
        hipLaunchKernelGGL(ngp_mlp5, gm, bm, 0, stream,
                           dc, feats_pk, idxbuf, cnt, w1a, b1a, w1b, b1b,
                           w2a, b2a, w2b, b2b, w2c, b2c, out);
    } else {
        dim3 grid(NPTS / 256), block(256);
        hipLaunchKernelGGL(ngp_fused, grid, block, 0, stream,
                           x, d, tables, w1a, b1a, w1b, b1b,
                           w2a, b2a, w2b, b2b, w2c, b2c, out);
    }
}

// Round 6
// 268.682 us; speedup vs baseline: 1.3929x; 1.0789x over previous
//
#include <hip/hip_runtime.h>
#include <math.h>

#define NPTS 524288
#define HALF (NPTS / 2)
#define TSZ  524288
#define TMASK (TSZ - 1)
#define FP8SCALE 4096.0f
#define FP8INV   (1.0f / 4096.0f)

typedef __attribute__((ext_vector_type(8))) short v8s;   // 8 x bf16 (4 VGPR)
typedef __attribute__((ext_vector_type(4))) float v4f;   // MFMA C/D frag
typedef __attribute__((ext_vector_type(2))) float v2f;

#define MFMA16(a, b, c) __builtin_amdgcn_mfma_f32_16x16x32_bf16(a, b, c, 0, 0, 0)

__device__ __constant__ float NLf[16] = {
    16.f, 22.f, 30.f, 42.f, 58.f, 80.f, 110.f, 152.f,
    209.f, 288.f, 397.f, 547.f, 754.f, 1039.f, 1432.f, 1974.f
};

#define CEILX 0xE2
#define CEILY 0xD4
#define CEILZ 0xB8

__device__ __forceinline__ short bf16r(float v) {  // f32 -> bf16 RNE
    unsigned b = __float_as_uint(v);
    b += 0x7FFFu + ((b >> 16) & 1u);
    return (short)(b >> 16);
}
__device__ __forceinline__ unsigned packbf(float a, float b) {
    return (unsigned)(unsigned short)bf16r(a) | ((unsigned)(unsigned short)bf16r(b) << 16);
}
__device__ __forceinline__ unsigned sel4(uint4 t, unsigned i) {
    const unsigned ab = (i & 1u) ? t.y : t.x;
    const unsigned cd = (i & 1u) ? t.w : t.z;
    return (i & 2u) ? cd : ab;
}
__device__ __forceinline__ unsigned sel8(uint4 t, unsigned i) {  // pick ushort i of 8
    const unsigned w = sel4(t, i >> 1);
    return (i & 1u) ? (w >> 16) : (w & 0xFFFFu);
}

// ---- kernel 0: pack fp32 tables -> 2xfp8 e4m3 (2 B/entry), scale 4096 ------
// Values are +-1e-4: x4096 -> +-0.41, comfortably in e4m3 normal range.
// Feats error ~6% of 1e-4 -> ~1e-6 at outputs (bf16 output quantum is 2^-8).
__global__ __launch_bounds__(256) void pack_tables(
    const float4* __restrict__ tbl, unsigned* __restrict__ out,
    unsigned* __restrict__ idxbuf, unsigned* __restrict__ cnt)
{
    const int idx = blockIdx.x * 256 + threadIdx.x;   // handles 2 entries
    const float4 t = tbl[idx];
    const unsigned lo = (unsigned)__builtin_amdgcn_cvt_pk_fp8_f32(
                            t.x * FP8SCALE, t.y * FP8SCALE, 0, false) & 0xFFFFu;
    const unsigned hi = (unsigned)__builtin_amdgcn_cvt_pk_fp8_f32(
                            t.z * FP8SCALE, t.w * FP8SCALE, 0, false) & 0xFFFFu;
    out[idx] = lo | (hi << 16);
    if (idx < NPTS) idxbuf[idx] = 0xFFFFFFFFu;        // sentinel for tail tiles
    if (idx == 0) cnt[0] = 0u;
}

// ---- kernel 0b: mask + stream compaction (block-aggregated atomic) ---------
__global__ __launch_bounds__(1024) void ngp_compact2(
    const float* __restrict__ x, const float* __restrict__ d,
    unsigned* __restrict__ idxbuf, float* __restrict__ xc,
    float* __restrict__ dc, unsigned* __restrict__ cnt,
    float* __restrict__ out)
{
    __shared__ unsigned sWCnt[16];
    __shared__ unsigned sBase;

    const int tid  = threadIdx.x;
    const int wv   = tid >> 6, lane = tid & 63;
    const int i    = blockIdx.x * 1024 + tid;

    const float x0 = x[3*i+0], x1 = x[3*i+1], x2 = x[3*i+2];
    const float xs0 = x0 / 3.0f, xs1 = x1 / 3.0f, xs2 = x2 / 3.0f;
    const bool act = (fabsf(xs0) < 0.5f) && (fabsf(xs1) < 0.5f) && (fabsf(xs2) < 0.5f);
    if (!act) {
        out[3*i+0] = 0.f; out[3*i+1] = 0.f; out[3*i+2] = 0.f;
        out[3*NPTS + i] = 0.f;
    }
    const unsigned long long mb = __ballot(act);
    if (lane == 0) sWCnt[wv] = (unsigned)__popcll(mb);
    __syncthreads();
    if (tid == 0) {
        unsigned tot = 0;
        #pragma unroll
        for (int w = 0; w < 16; ++w) tot += sWCnt[w];
        sBase = atomicAdd(cnt, tot);
    }
    __syncthreads();
    if (act) {
        unsigned off = sBase;
        for (int w = 0; w < wv; ++w) off += sWCnt[w];
        off += (unsigned)__popcll(mb & ((1ull << lane) - 1ull));
        idxbuf[off] = (unsigned)i;
        xc[3*off+0] = x0; xc[3*off+1] = x1; xc[3*off+2] = x2;
        dc[3*off+0] = d[3*i+0]; dc[3*off+1] = d[3*i+1]; dc[3*off+2] = d[3*i+2];
    }
}

// ---- kernel 1: hash gather, fp8 tables (R6) --------------------------------
// 2B entries: uint4 covers 8 entries -> x-pair merged when diff<=7 (87.5% vs
// 75%), and per-level L2 footprint halves (2MiB->1MiB) -> fewer HBM misses.
// Unpack via v_cvt_pk_f32_fp8; accumulate scaled, multiply by exact 2^-12.
__global__ __launch_bounds__(256) void ngp_hash6(
    const float* __restrict__ xc, const unsigned short* __restrict__ tables_pk,
    const unsigned* __restrict__ cnt, unsigned* __restrict__ feats_pk)
{
    __shared__ float sX[768];
    const int NC = (int)cnt[0];
    if (blockIdx.x * 256 >= NC) return;       // compacted tail: nothing to do

    const int tid = threadIdx.x;
    const int l = blockIdx.y;
    const float n = NLf[l];
    const unsigned short* tbl = tables_pk + (size_t)l * TSZ;

    for (int r = tid; r < 768; r += 256)
        sX[r] = xc[(size_t)blockIdx.x * 768 + r];
    __syncthreads();

    const int j = blockIdx.x * 256 + tid;     // compact index (>=NC rows: unused)
    const float xu0 = sX[tid * 3 + 0] / 3.0f + 0.5f;
    const float xu1 = sX[tid * 3 + 1] / 3.0f + 0.5f;
    const float xu2 = sX[tid * 3 + 2] / 3.0f + 0.5f;

    const float p0 = xu0 * n, p1 = xu1 * n, p2 = xu2 * n;
    const float f0 = floorf(p0), f1 = floorf(p1), f2 = floorf(p2);
    const float fr0 = p0 - f0, fr1 = p1 - f1, fr2 = p2 - f2;
    const float g0 = 1.f - fr0, g1 = 1.f - fr1, g2 = 1.f - fr2;
    const unsigned uvf0 = (unsigned)(int)f0;
    const unsigned uvc0 = (unsigned)(int)ceilf(p0);
    const unsigned syf = (unsigned)(int)f1 * 2654435761u;
    const unsigned syc = (unsigned)(int)ceilf(p1) * 2654435761u;
    const unsigned szf = (unsigned)(int)f2 * 805459861u;
    const unsigned szc = (unsigned)(int)ceilf(p2) * 805459861u;

    const float w0 = g0 * g1 * g2,  w1 = fr0 * g1 * g2;
    const float w2 = g0 * fr1 * g2, w6 = g0 * fr1 * fr2;
    const float w3 = fr0 * fr1 * g2, w5 = fr0 * g1 * fr2;
    const float w4 = g0 * g1 * fr2, w7 = fr0 * fr1 * fr2;

    const unsigned Ss[4] = { syf ^ szf, syc ^ szf, syf ^ szc, syc ^ szc };
    const float wf[4] = { w0, w2, w3, w4 };
    const float wc[4] = { w1, w6, w5, w7 };

    float a0 = 0.f, a1 = 0.f;
    #pragma unroll
    for (int pr = 0; pr < 4; ++pr) {
        const unsigned hf = (Ss[pr] ^ uvf0) & TMASK;
        const unsigned hc = (Ss[pr] ^ uvc0) & TMASK;
        const unsigned diff = hf ^ hc;
        const uint4 tv = *(const uint4*)(tbl + (hf & ~7u));   // 8 entries
        const unsigned ef = sel8(tv, hf & 7u);
        unsigned ec;
        if (diff <= 7u) ec = sel8(tv, hc & 7u);
        else            ec = (unsigned)tbl[hc];
        const v2f ff = __builtin_amdgcn_cvt_pk_f32_fp8((int)ef, false);
        const v2f fc = __builtin_amdgcn_cvt_pk_f32_fp8((int)ec, false);
        a0 = fmaf(wf[pr], ff.x, a0);
        a1 = fmaf(wf[pr], ff.y, a1);
        a0 = fmaf(wc[pr], fc.x, a0);
        a1 = fmaf(wc[pr], fc.y, a1);
    }
    a0 *= FP8INV;  // exact pow2 unscale
    a1 *= FP8INV;
    feats_pk[(size_t)l * NPTS + j] = packbf(a0, a1);
}

// ---- kernel 2: MFMA MLP on compacted points (R5 verified) ------------------
#define PZ 72   // z-buffer pitch in shorts (144 B, 16B-aligned)
#define SWL(row) ((((row) >> 2) & 3) << 4)

__global__ __launch_bounds__(512) void ngp_mlp5(
    const float* __restrict__ dc,
    const unsigned* __restrict__ feats_pk, const unsigned* __restrict__ idxbuf,
    const unsigned* __restrict__ cnt,
    const float* __restrict__ w1a, const float* __restrict__ b1a,
    const float* __restrict__ w1b, const float* __restrict__ b1b,
    const float* __restrict__ w2a, const float* __restrict__ b2a,
    const float* __restrict__ w2b, const float* __restrict__ b2b,
    const float* __restrict__ w2c, const float* __restrict__ b2c,
    float* __restrict__ out)
{
    __shared__ short sW1a[64 * 40];
    __shared__ short sW1b[16 * 72];
    __shared__ short sW2a[64 * 72];
    __shared__ short sW2b[64 * 72];
    __shared__ short sW2c[16 * 72];
    __shared__ short sZ[8 * 16 * PZ];

    const int NC = (int)cnt[0];
    if (blockIdx.x * 128 >= NC) return;       // whole block beyond compact set

    const int tid = threadIdx.x;

    for (int idx = tid; idx < 32 * 64; idx += 512) {
        const int k = idx >> 6, n2 = idx & 63;
        sW1a[n2 * 40 + k] = bf16r(w1a[k * 64 + n2]);
    }
    for (int idx = tid; idx < 64 * 16; idx += 512) {
        const int k = idx >> 4, n2 = idx & 15;
        sW1b[n2 * 72 + k] = bf16r(w1b[k * 16 + n2]);
    }
    for (int idx = tid; idx < 64 * 64; idx += 512) {
        const int k = idx >> 6, n2 = idx & 63;
        sW2a[n2 * 72 + k] = bf16r(k < 43 ? w2a[k * 64 + n2] : 0.f);
    }
    for (int idx = tid; idx < 64 * 64; idx += 512) {
        const int k = idx >> 6, n2 = idx & 63;
        sW2b[n2 * 72 + k] = bf16r(w2b[k * 64 + n2]);
    }
    for (int idx = tid; idx < 64 * 16; idx += 512) {
        const int k = idx >> 4, n2 = idx & 15;
        sW2c[n2 * 72 + k] = bf16r(n2 < 3 ? w2c[k * 3 + n2] : 0.f);
    }
    __syncthreads();

    const int wave = tid >> 6, lane = tid & 63;
    const int m = lane & 15, q = lane >> 4;
    short* zb = &sZ[wave * 16 * PZ];

    const int j0 = (blockIdx.x * 8 + wave) * 16;   // this wave's compact tile
    if (j0 >= NC) return;                          // after staging+sync: safe

    float bb1a[4], bb2a[4], bb2b[4];
    #pragma unroll
    for (int ct = 0; ct < 4; ++ct) {
        bb1a[ct] = b1a[ct * 16 + m];
        bb2a[ct] = b2a[ct * 16 + m];
        bb2b[ct] = b2b[ct * 16 + m];
    }
    const float bb1b = b1b[m];
    const float bb2c = (m < 3) ? b2c[m] : 0.f;

    // ---- feats -> z cols [0,32), swizzled ------------------------------
    #pragma unroll
    for (int it = 0; it < 4; ++it) {
        const int l = it * 4 + q;
        *(unsigned*)(zb + m * PZ + ((2 * l) ^ SWL(m))) =
            feats_pk[(size_t)l * NPTS + j0 + m];
    }

    // ---- layer 1a: feats(32) -> 64, relu --------------------------------
    {
        const v8s a0 = *(const v8s*)(zb + m * PZ + ((q * 8) ^ SWL(m)));
        #pragma unroll
        for (int ct = 0; ct < 4; ++ct) {
            const float bv = bb1a[ct];
            v4f acc = {bv, bv, bv, bv};
            acc = MFMA16(a0, *(const v8s*)(sW1a + (ct * 16 + m) * 40 + q * 8), acc);
            #pragma unroll
            for (int r = 0; r < 4; ++r)
                zb[(q * 4 + r) * PZ + ((ct * 16 + m) ^ (q << 4))] = bf16r(fmaxf(acc[r], 0.f));
        }
    }

    // ---- layer 1b: 64 -> 16 (h; h[0] is log_sigma) ----------------------
    v4f hacc;
    {
        const v8s a10 = *(const v8s*)(zb + m * PZ + ((q * 8) ^ SWL(m)));
        const v8s a11 = *(const v8s*)(zb + m * PZ + ((32 + q * 8) ^ SWL(m)));
        v4f hv = {bb1b, bb1b, bb1b, bb1b};
        hv = MFMA16(a10, *(const v8s*)(sW1b + m * 72 + q * 8), hv);
        hv = MFMA16(a11, *(const v8s*)(sW1b + m * 72 + 32 + q * 8), hv);
        hacc = hv;
        #pragma unroll
        for (int r = 0; r < 4; ++r)
            zb[(q * 4 + r) * PZ + (m ^ (q << 4))] = bf16r(hv[r]);
    }

    // ---- posenc(dc) into z cols [16,43), zero pad [48,64) ---------------
    {
        const float dd0 = dc[3*(j0+m)+0], dd1 = dc[3*(j0+m)+1], dd2 = dc[3*(j0+m)+2];
        v8s pk;
        #pragma unroll
        for (int jj = 0; jj < 8; ++jj) {
            const int k = 16 + q * 8 + jj;
            float v;
            if (k < 19) {
                v = (k == 16) ? dd0 : ((k == 17) ? dd1 : dd2);
            } else if (k < 43) {
                const int idx = k - 19;
                const int e = idx / 6, w = idx - 6 * e;
                const float base = (w == 0 || w == 3) ? dd0 : ((w == 1 || w == 4) ? dd1 : dd2);
                const float s = (float)(1 << e) * base;
                v = (w < 3) ? __sinf(s) : __cosf(s);
            } else {
                v = 0.f;
            }
            pk[jj] = bf16r(v);
        }
        *(v8s*)(zb + m * PZ + ((16 + q * 8) ^ SWL(m))) = pk;
        *(unsigned long long*)(zb + m * PZ + ((48 + q * 4) ^ SWL(m))) = 0ull;
    }

    // ---- layer 2a: z(43,pad64) -> 64, relu ------------------------------
    {
        const v8s a20 = *(const v8s*)(zb + m * PZ + ((q * 8) ^ SWL(m)));
        const v8s a21 = *(const v8s*)(zb + m * PZ + ((32 + q * 8) ^ SWL(m)));
        #pragma unroll
        for (int ct = 0; ct < 4; ++ct) {
            const float bv = bb2a[ct];
            v4f acc = {bv, bv, bv, bv};
            acc = MFMA16(a20, *(const v8s*)(sW2a + (ct * 16 + m) * 72 + q * 8), acc);
            acc = MFMA16(a21, *(const v8s*)(sW2a + (ct * 16 + m) * 72 + 32 + q * 8), acc);
            #pragma unroll
            for (int r = 0; r < 4; ++r)
                zb[(q * 4 + r) * PZ + ((ct * 16 + m) ^ (q << 4))] = bf16r(fmaxf(acc[r], 0.f));
        }
    }

    // ---- layer 2b: 64 -> 64, relu ---------------------------------------
    {
        const v8s a20 = *(const v8s*)(zb + m * PZ + ((q * 8) ^ SWL(m)));
        const v8s a21 = *(const v8s*)(zb + m * PZ + ((32 + q * 8) ^ SWL(m)));
        #pragma unroll
        for (int ct = 0; ct < 4; ++ct) {
            const float bv = bb2b[ct];
            v4f acc = {bv, bv, bv, bv};
            acc = MFMA16(a20, *(const v8s*)(sW2b + (ct * 16 + m) * 72 + q * 8), acc);
            acc = MFMA16(a21, *(const v8s*)(sW2b + (ct * 16 + m) * 72 + 32 + q * 8), acc);
            #pragma unroll
            for (int r = 0; r < 4; ++r)
                zb[(q * 4 + r) * PZ + ((ct * 16 + m) ^ (q << 4))] = bf16r(fmaxf(acc[r], 0.f));
        }
    }

    // ---- layer 2c: 64 -> 3, sigmoid, scatter store ----------------------
    {
        const v8s a30 = *(const v8s*)(zb + m * PZ + ((q * 8) ^ SWL(m)));
        const v8s a31 = *(const v8s*)(zb + m * PZ + ((32 + q * 8) ^ SWL(m)));
        v4f cacc = {bb2c, bb2c, bb2c, bb2c};
        cacc = MFMA16(a30, *(const v8s*)(sW2c + m * 72 + q * 8), cacc);
        cacc = MFMA16(a31, *(const v8s*)(sW2c + m * 72 + 32 + q * 8), cacc);

        if (m < 3) {
            #pragma unroll
            for (int r = 0; r < 4; ++r) {
                const unsigned pj = idxbuf[j0 + q * 4 + r];
                if (pj < (unsigned)NPTS) {
                    const float cv = 1.0f / (1.0f + __expf(-cacc[r]));
                    out[3 * pj + m] = cv;
                }
            }
        }
        if (m == 0) {
            #pragma unroll
            for (int r = 0; r < 4; ++r) {
                const unsigned pj = idxbuf[j0 + q * 4 + r];
                if (pj < (unsigned)NPTS)
                    out[3 * NPTS + pj] = __expf(hacc[r]);
            }
        }
    }
}

// ---------------- fallback: fused VALU kernel (if ws too small) -------------
__global__ __launch_bounds__(256) void ngp_fused(
    const float* __restrict__ x, const float* __restrict__ d,
    const float* __restrict__ tables,
    const float* __restrict__ w1a, const float* __restrict__ b1a,
    const float* __restrict__ w1b, const float* __restrict__ b1b,
    const float* __restrict__ w2a, const float* __restrict__ b2a,
    const float* __restrict__ w2b, const float* __restrict__ b2b,
    const float* __restrict__ w2c, const float* __restrict__ b2c,
    float* __restrict__ out)
{
    const int i = blockIdx.x * 256 + threadIdx.x;
    if (i >= NPTS) return;
    const float xs0 = x[3*i+0] / 3.0f;
    const float xs1 = x[3*i+1] / 3.0f;
    const float xs2 = x[3*i+2] / 3.0f;
    const bool mask = (fabsf(xs0) < 0.5f) & (fabsf(xs1) < 0.5f) & (fabsf(xs2) < 0.5f);
    const float xu0 = xs0 + 0.5f, xu1 = xs1 + 0.5f, xu2 = xs2 + 0.5f;

    float feats[32];
    #pragma unroll
    for (int l = 0; l < 16; ++l) {
        const float n = NLf[l];
        const float p0 = xu0 * n, p1 = xu1 * n, p2 = xu2 * n;
        const float f0 = floorf(p0), f1 = floorf(p1), f2 = floorf(p2);
        const float fr0 = p0 - f0, fr1 = p1 - f1, fr2 = p2 - f2;
        const int vf0 = (int)f0, vf1 = (int)f1, vf2 = (int)f2;
        const int vc0 = (int)ceilf(p0), vc1 = (int)ceilf(p1), vc2 = (int)ceilf(p2);
        const float2* tbl = (const float2*)(tables + (size_t)l * (TSZ * 2));
        float a0 = 0.f, a1 = 0.f;
        #pragma unroll
        for (int k = 0; k < 8; ++k) {
            const unsigned vx = (unsigned)(((CEILX >> k) & 1) ? vc0 : vf0);
            const unsigned vy = (unsigned)(((CEILY >> k) & 1) ? vc1 : vf1);
            const unsigned vz = (unsigned)(((CEILZ >> k) & 1) ? vc2 : vf2);
            const unsigned h = (vx ^ (vy * 2654435761u) ^ (vz * 805459861u)) & TMASK;
            const float wx = (k & 1)        ? fr0 : 1.0f - fr0;
            const float wy = ((k >> 1) & 1) ? fr1 : 1.0f - fr1;
            const float wz = ((k >> 2) & 1) ? fr2 : 1.0f - fr2;
            const float wgt = wx * wy * wz;
            const float2 t = tbl[h];
            a0 = fmaf(wgt, t.x, a0);
            a1 = fmaf(wgt, t.y, a1);
        }
        feats[2*l] = a0; feats[2*l+1] = a1;
    }

    float h2v[16];
    #pragma unroll
    for (int j = 0; j < 16; ++j) h2v[j] = b1b[j];
    #pragma unroll
    for (int c = 0; c < 4; ++c) {
        float h1c[16];
        #pragma unroll
        for (int jj = 0; jj < 16; ++jj) h1c[jj] = b1a[16*c + jj];
        #pragma unroll
        for (int i2 = 0; i2 < 32; ++i2) {
            const float f = feats[i2];
            #pragma unroll
            for (int jj = 0; jj < 16; ++jj)
                h1c[jj] = fmaf(f, w1a[i2*64 + 16*c + jj], h1c[jj]);
        }
        #pragma unroll
        for (int jj = 0; jj < 16; ++jj) {
            const float f = fmaxf(h1c[jj], 0.f);
            #pragma unroll
            for (int t = 0; t < 16; ++t)
                h2v[t] = fmaf(f, w1b[(16*c + jj)*16 + t], h2v[t]);
        }
    }

    float z1[64];
    #pragma unroll
    for (int j = 0; j < 64; ++j) z1[j] = b2a[j];
    #pragma unroll
    for (int i2 = 0; i2 < 16; ++i2) {
        const float f = h2v[i2];
        #pragma unroll
        for (int j = 0; j < 64; ++j) z1[j] = fmaf(f, w2a[i2*64 + j], z1[j]);
    }
    const float d0 = d[3*i+0], d1 = d[3*i+1], d2 = d[3*i+2];
    {
        const float* r = w2a + 16*64;
        #pragma unroll
        for (int j = 0; j < 64; ++j) z1[j] = fmaf(d0, r[j], z1[j]);
        r = w2a + 17*64;
        #pragma unroll
        for (int j = 0; j < 64; ++j) z1[j] = fmaf(d1, r[j], z1[j]);
        r = w2a + 18*64;
        #pragma unroll
        for (int j = 0; j < 64; ++j) z1[j] = fmaf(d2, r[j], z1[j]);
    }
    #pragma unroll
    for (int e = 0; e < 4; ++e) {
        const float mm = (float)(1 << e);
        const float dv[3] = {d0, d1, d2};
        #pragma unroll
        for (int a = 0; a < 3; ++a) {
            const float sv = __sinf(mm * dv[a]);
            const float* rs = w2a + (19 + 6*e + a)*64;
            #pragma unroll
            for (int j = 0; j < 64; ++j) z1[j] = fmaf(sv, rs[j], z1[j]);
        }
        #pragma unroll
        for (int a = 0; a < 3; ++a) {
            const float cv = __cosf(mm * dv[a]);
            const float* rc = w2a + (19 + 6*e + 3 + a)*64;
            #pragma unroll
            for (int j = 0; j < 64; ++j) z1[j] = fmaf(cv, rc[j], z1[j]);
        }
    }
    #pragma unroll
    for (int j = 0; j < 64; ++j) z1[j] = fmaxf(z1[j], 0.f);

    float ca = b2c[0], cb = b2c[1], cc = b2c[2];
    #pragma unroll
    for (int jc = 0; jc < 64; jc += 16) {
        float acc[16];
        #pragma unroll
        for (int jj = 0; jj < 16; ++jj) acc[jj] = b2b[jc + jj];
        #pragma unroll
        for (int i2 = 0; i2 < 64; ++i2) {
            const float f = z1[i2];
            #pragma unroll
            for (int jj = 0; jj < 16; ++jj)
                acc[jj] = fmaf(f, w2b[i2*64 + jc + jj], acc[jj]);
        }
        #pragma unroll
        for (int jj = 0; jj < 16; ++jj) {
            const float v = fmaxf(acc[jj], 0.f);
            ca = fmaf(v, w2c[(jc + jj)*3 + 0], ca);
            cb = fmaf(v, w2c[(jc + jj)*3 + 1], cb);
            cc = fmaf(v, w2c[(jc + jj)*3 + 2], cc);
        }
    }

    float r = 1.0f / (1.0f + __expf(-ca));
    float g = 1.0f / (1.0f + __expf(-cb));
    float b = 1.0f / (1.0f + __expf(-cc));
    float sigma;
    if (mask) { sigma = __expf(h2v[0]); }
    else { r = 0.f; g = 0.f; b = 0.f; sigma = 0.f; }
    out[3*i + 0] = r;
    out[3*i + 1] = g;
    out[3*i + 2] = b;
    out[3*NPTS + i] = sigma;
}

extern "C" void kernel_launch(void* const* d_in, const int* in_sizes, int n_in,
                              void* d_out, int out_size, void* d_ws, size_t ws_size,
                              hipStream_t stream) {
    const float* x      = (const float*)d_in[0];
    const float* d      = (const float*)d_in[1];
    const float* tables = (const float*)d_in[2];
    const float* w1a    = (const float*)d_in[3];
    const float* b1a    = (const float*)d_in[4];
    const float* w1b    = (const float*)d_in[5];
    const float* b1b    = (const float*)d_in[6];
    const float* w2a    = (const float*)d_in[7];
    const float* b2a    = (const float*)d_in[8];
    const float* w2b    = (const float*)d_in[9];
    const float* b2b    = (const float*)d_in[10];
    const float* w2c    = (const float*)d_in[11];
    const float* b2c    = (const float*)d_in[12];
    float* out = (float*)d_out;

    // ws layout (u32 units): [0,16N) feats_pk; [16N,24N) tables_pk (fp8 2B/e);
    // [24N,25N) idxbuf; [25N] counter; [26N,29N) xc; [29N,32N) dc
    const size_t need = (size_t)32 * NPTS * 4;   // 64 MiB
    if (ws_size >= need) {
        unsigned* base      = (unsigned*)d_ws;
        unsigned* feats_pk  = base;
        unsigned* tables_pk = base + (size_t)16 * NPTS;
        unsigned* idxbuf    = base + (size_t)24 * NPTS;
        unsigned* cnt       = base + (size_t)25 * NPTS;
        float*    xc        = (float*)(base + (size_t)26 * NPTS);
        float*    dc        = (float*)(base + (size_t)29 * NPTS);

        dim3 gp(16 * TSZ / (256 * 2)), bp(256);
        hipLaunchKernelGGL(pack_tables, gp, bp, 0, stream,
                           (const float4*)tables, tables_pk, idxbuf, cnt);

        dim3 gc(NPTS / 1024), bc(1024);
        hipLaunchKernelGGL(ngp_compact2, gc, bc, 0, stream,
                           x, d, idxbuf, xc, dc, cnt, out);

        dim3 gh(NPTS / 256, 16), bh(256);
        hipLaunchKernelGGL(ngp_hash6, gh, bh, 0, stream,
                           xc, (const unsigned short*)tables_pk, cnt, feats_pk);

        dim3 gm(NPTS / 128), bm(512);
        hipLaunchKernelGGL(ngp_mlp5, gm, bm, 0, stream,
                           dc, feats_pk, idxbuf, cnt, w1a, b1a, w1b, b1b,
                           w2a, b2a, w2b, b2b, w2c, b2c, out);
    } else {
        dim3 grid(NPTS / 256), block(256);
        hipLaunchKernelGGL(ngp_fused, grid, block, 0, stream,
                           x, d, tables, w1a, b1a, w1b, b1b,
                           w2a, b2a, w2b, b2b, w2c, b2c, out);
    }
}

// Round 7
// 265.051 us; speedup vs baseline: 1.4120x; 1.0137x over previous
//
#include <hip/hip_runtime.h>
#include <math.h>

#define NPTS 524288
#define HALF (NPTS / 2)
#define TSZ  524288
#define TMASK (TSZ - 1)
#define FP8SCALE 4096.0f
#define FP8INV   (1.0f / 4096.0f)

typedef __attribute__((ext_vector_type(8))) short v8s;   // 8 x bf16 (4 VGPR)
typedef __attribute__((ext_vector_type(4))) float v4f;   // MFMA C/D frag
typedef __attribute__((ext_vector_type(2))) float v2f;

#define MFMA16(a, b, c) __builtin_amdgcn_mfma_f32_16x16x32_bf16(a, b, c, 0, 0, 0)

__device__ __constant__ float NLf[16] = {
    16.f, 22.f, 30.f, 42.f, 58.f, 80.f, 110.f, 152.f,
    209.f, 288.f, 397.f, 547.f, 754.f, 1039.f, 1432.f, 1974.f
};

#define CEILX 0xE2
#define CEILY 0xD4
#define CEILZ 0xB8

__device__ __forceinline__ short bf16r(float v) {  // f32 -> bf16 RNE
    unsigned b = __float_as_uint(v);
    b += 0x7FFFu + ((b >> 16) & 1u);
    return (short)(b >> 16);
}
__device__ __forceinline__ unsigned packbf(float a, float b) {
    return (unsigned)(unsigned short)bf16r(a) | ((unsigned)(unsigned short)bf16r(b) << 16);
}
__device__ __forceinline__ unsigned sel4(uint4 t, unsigned i) {
    const unsigned ab = (i & 1u) ? t.y : t.x;
    const unsigned cd = (i & 1u) ? t.w : t.z;
    return (i & 2u) ? cd : ab;
}
__device__ __forceinline__ unsigned sel8(uint4 t, unsigned i) {  // pick ushort i of 8
    const unsigned w = sel4(t, i >> 1);
    return (i & 1u) ? (w >> 16) : (w & 0xFFFFu);
}

// ---- kernel 0: pack fp32 tables -> 2xfp8 e4m3 (2 B/entry), scale 4096 ------
__global__ __launch_bounds__(256) void pack_tables(
    const float4* __restrict__ tbl, unsigned* __restrict__ out,
    unsigned* __restrict__ idxbuf, unsigned* __restrict__ cnt)
{
    const int idx = blockIdx.x * 256 + threadIdx.x;   // handles 2 entries
    const float4 t = tbl[idx];
    const unsigned lo = (unsigned)__builtin_amdgcn_cvt_pk_fp8_f32(
                            t.x * FP8SCALE, t.y * FP8SCALE, 0, false) & 0xFFFFu;
    const unsigned hi = (unsigned)__builtin_amdgcn_cvt_pk_fp8_f32(
                            t.z * FP8SCALE, t.w * FP8SCALE, 0, false) & 0xFFFFu;
    out[idx] = lo | (hi << 16);
    if (idx < NPTS) idxbuf[idx] = 0xFFFFFFFFu;        // sentinel for tail tiles
    if (idx == 0) cnt[0] = 0u;
}

// ---- kernel 0a: pre-pack MLP weights into exact LDS layouts (bf16) ---------
// R7: each MLP block re-staged + re-converted 12.5k f32 weights (~51M bf16r
// total, 133MB reads) for 128 points. Convert ONCE here; MLP copies uint4s.
#define W1A_OFF 0        // 64 x 40
#define W1B_OFF 2560     // 16 x 72
#define W2A_OFF 3712     // 64 x 72
#define W2B_OFF 8320     // 64 x 72
#define W2C_OFF 12928    // 16 x 72
#define WPK_TOT 14080    // shorts (28160 B = 1760 uint4)

__global__ __launch_bounds__(1024) void ngp_packw(
    const float* __restrict__ w1a, const float* __restrict__ w1b,
    const float* __restrict__ w2a, const float* __restrict__ w2b,
    const float* __restrict__ w2c, unsigned short* __restrict__ wpk)
{
    const int s = blockIdx.x * 1024 + threadIdx.x;
    if (s >= WPK_TOT) return;
    float v = 0.f;
    if (s < W1B_OFF) {                     // sW1a: n(64) x k(40), k<32 live
        const int r = s - W1A_OFF, n = r / 40, k = r % 40;
        v = (k < 32) ? w1a[k * 64 + n] : 0.f;
    } else if (s < W2A_OFF) {              // sW1b: n(16) x k(72), k<64 live
        const int r = s - W1B_OFF, n = r / 72, k = r % 72;
        v = (k < 64) ? w1b[k * 16 + n] : 0.f;
    } else if (s < W2B_OFF) {              // sW2a: n(64) x k(72), k<43 live
        const int r = s - W2A_OFF, n = r / 72, k = r % 72;
        v = (k < 43) ? w2a[k * 64 + n] : 0.f;
    } else if (s < W2C_OFF) {              // sW2b: n(64) x k(72), k<64 live
        const int r = s - W2B_OFF, n = r / 72, k = r % 72;
        v = (k < 64) ? w2b[k * 64 + n] : 0.f;
    } else {                               // sW2c: n(16) x k(72), n<3,k<64 live
        const int r = s - W2C_OFF, n = r / 72, k = r % 72;
        v = (k < 64 && n < 3) ? w2c[k * 3 + n] : 0.f;
    }
    wpk[s] = (unsigned short)bf16r(v);
}

// ---- kernel 0b: mask + stream compaction (block-aggregated atomic) ---------
__global__ __launch_bounds__(1024) void ngp_compact2(
    const float* __restrict__ x, const float* __restrict__ d,
    unsigned* __restrict__ idxbuf, float* __restrict__ xc,
    float* __restrict__ dc, unsigned* __restrict__ cnt,
    float* __restrict__ out)
{
    __shared__ unsigned sWCnt[16];
    __shared__ unsigned sBase;

    const int tid  = threadIdx.x;
    const int wv   = tid >> 6, lane = tid & 63;
    const int i    = blockIdx.x * 1024 + tid;

    const float x0 = x[3*i+0], x1 = x[3*i+1], x2 = x[3*i+2];
    const float xs0 = x0 / 3.0f, xs1 = x1 / 3.0f, xs2 = x2 / 3.0f;
    const bool act = (fabsf(xs0) < 0.5f) && (fabsf(xs1) < 0.5f) && (fabsf(xs2) < 0.5f);
    if (!act) {
        out[3*i+0] = 0.f; out[3*i+1] = 0.f; out[3*i+2] = 0.f;
        out[3*NPTS + i] = 0.f;
    }
    const unsigned long long mb = __ballot(act);
    if (lane == 0) sWCnt[wv] = (unsigned)__popcll(mb);
    __syncthreads();
    if (tid == 0) {
        unsigned tot = 0;
        #pragma unroll
        for (int w = 0; w < 16; ++w) tot += sWCnt[w];
        sBase = atomicAdd(cnt, tot);
    }
    __syncthreads();
    if (act) {
        unsigned off = sBase;
        for (int w = 0; w < wv; ++w) off += sWCnt[w];
        off += (unsigned)__popcll(mb & ((1ull << lane) - 1ull));
        idxbuf[off] = (unsigned)i;
        xc[3*off+0] = x0; xc[3*off+1] = x1; xc[3*off+2] = x2;
        dc[3*off+0] = d[3*i+0]; dc[3*off+1] = d[3*i+1]; dc[3*off+2] = d[3*i+2];
    }
}

// ---- kernel 1: hash gather, fp8 tables (R6 verified: 94us) -----------------
__global__ __launch_bounds__(256) void ngp_hash6(
    const float* __restrict__ xc, const unsigned short* __restrict__ tables_pk,
    const unsigned* __restrict__ cnt, unsigned* __restrict__ feats_pk)
{
    __shared__ float sX[768];
    const int NC = (int)cnt[0];
    if (blockIdx.x * 256 >= NC) return;       // compacted tail: nothing to do

    const int tid = threadIdx.x;
    const int l = blockIdx.y;
    const float n = NLf[l];
    const unsigned short* tbl = tables_pk + (size_t)l * TSZ;

    for (int r = tid; r < 768; r += 256)
        sX[r] = xc[(size_t)blockIdx.x * 768 + r];
    __syncthreads();

    const int j = blockIdx.x * 256 + tid;     // compact index (>=NC rows: unused)
    const float xu0 = sX[tid * 3 + 0] / 3.0f + 0.5f;
    const float xu1 = sX[tid * 3 + 1] / 3.0f + 0.5f;
    const float xu2 = sX[tid * 3 + 2] / 3.0f + 0.5f;

    const float p0 = xu0 * n, p1 = xu1 * n, p2 = xu2 * n;
    const float f0 = floorf(p0), f1 = floorf(p1), f2 = floorf(p2);
    const float fr0 = p0 - f0, fr1 = p1 - f1, fr2 = p2 - f2;
    const float g0 = 1.f - fr0, g1 = 1.f - fr1, g2 = 1.f - fr2;
    const unsigned uvf0 = (unsigned)(int)f0;
    const unsigned uvc0 = (unsigned)(int)ceilf(p0);
    const unsigned syf = (unsigned)(int)f1 * 2654435761u;
    const unsigned syc = (unsigned)(int)ceilf(p1) * 2654435761u;
    const unsigned szf = (unsigned)(int)f2 * 805459861u;
    const unsigned szc = (unsigned)(int)ceilf(p2) * 805459861u;

    const float w0 = g0 * g1 * g2,  w1 = fr0 * g1 * g2;
    const float w2 = g0 * fr1 * g2, w6 = g0 * fr1 * fr2;
    const float w3 = fr0 * fr1 * g2, w5 = fr0 * g1 * fr2;
    const float w4 = g0 * g1 * fr2, w7 = fr0 * fr1 * fr2;

    const unsigned Ss[4] = { syf ^ szf, syc ^ szf, syf ^ szc, syc ^ szc };
    const float wf[4] = { w0, w2, w3, w4 };
    const float wc[4] = { w1, w6, w5, w7 };

    float a0 = 0.f, a1 = 0.f;
    #pragma unroll
    for (int pr = 0; pr < 4; ++pr) {
        const unsigned hf = (Ss[pr] ^ uvf0) & TMASK;
        const unsigned hc = (Ss[pr] ^ uvc0) & TMASK;
        const unsigned diff = hf ^ hc;
        const uint4 tv = *(const uint4*)(tbl + (hf & ~7u));   // 8 entries
        const unsigned ef = sel8(tv, hf & 7u);
        unsigned ec;
        if (diff <= 7u) ec = sel8(tv, hc & 7u);
        else            ec = (unsigned)tbl[hc];
        const v2f ff = __builtin_amdgcn_cvt_pk_f32_fp8((int)ef, false);
        const v2f fc = __builtin_amdgcn_cvt_pk_f32_fp8((int)ec, false);
        a0 = fmaf(wf[pr], ff.x, a0);
        a1 = fmaf(wf[pr], ff.y, a1);
        a0 = fmaf(wc[pr], fc.x, a0);
        a1 = fmaf(wc[pr], fc.y, a1);
    }
    a0 *= FP8INV;  // exact pow2 unscale
    a1 *= FP8INV;
    feats_pk[(size_t)l * NPTS + j] = packbf(a0, a1);
}

// ---- kernel 2: MFMA MLP, pre-packed weights, 4 tiles/wave ------------------
#define PZ 72   // z-buffer pitch in shorts (144 B, 16B-aligned)
#define SWL(row) ((((row) >> 2) & 3) << 4)

__global__ __launch_bounds__(512) void ngp_mlp6(
    const float* __restrict__ dc,
    const unsigned* __restrict__ feats_pk, const unsigned* __restrict__ idxbuf,
    const unsigned* __restrict__ cnt, const unsigned short* __restrict__ wpk,
    const float* __restrict__ b1a, const float* __restrict__ b1b,
    const float* __restrict__ b2a, const float* __restrict__ b2b,
    const float* __restrict__ b2c,
    float* __restrict__ out)
{
    __shared__ short sW[WPK_TOT];
    __shared__ short sZ[8 * 16 * PZ];

    const int NC = (int)cnt[0];
    if (blockIdx.x * 512 >= NC) return;       // whole block beyond compact set

    const int tid = threadIdx.x;
    for (int i = tid; i < WPK_TOT / 8; i += 512)
        ((uint4*)sW)[i] = ((const uint4*)wpk)[i];
    __syncthreads();

    const short* sW1a = sW + W1A_OFF;
    const short* sW1b = sW + W1B_OFF;
    const short* sW2a = sW + W2A_OFF;
    const short* sW2b = sW + W2B_OFF;
    const short* sW2c = sW + W2C_OFF;

    const int wave = tid >> 6, lane = tid & 63;
    const int m = lane & 15, q = lane >> 4;
    short* zb = &sZ[wave * 16 * PZ];

    float bb1a[4], bb2a[4], bb2b[4];
    #pragma unroll
    for (int ct = 0; ct < 4; ++ct) {
        bb1a[ct] = b1a[ct * 16 + m];
        bb2a[ct] = b2a[ct * 16 + m];
        bb2b[ct] = b2b[ct * 16 + m];
    }
    const float bb1b = b1b[m];
    const float bb2c = (m < 3) ? b2c[m] : 0.f;

    const int base = (blockIdx.x * 8 + wave) * 64;   // 4 consecutive tiles

    for (int t = 0; t < 4; ++t) {
        const int j0 = base + t * 16;
        if (j0 >= NC) break;

        // ---- feats -> z cols [0,32), swizzled --------------------------
        #pragma unroll
        for (int it = 0; it < 4; ++it) {
            const int l = it * 4 + q;
            *(unsigned*)(zb + m * PZ + ((2 * l) ^ SWL(m))) =
                feats_pk[(size_t)l * NPTS + j0 + m];
        }

        // ---- layer 1a: feats(32) -> 64, relu ---------------------------
        {
            const v8s a0 = *(const v8s*)(zb + m * PZ + ((q * 8) ^ SWL(m)));
            #pragma unroll
            for (int ct = 0; ct < 4; ++ct) {
                const float bv = bb1a[ct];
                v4f acc = {bv, bv, bv, bv};
                acc = MFMA16(a0, *(const v8s*)(sW1a + (ct * 16 + m) * 40 + q * 8), acc);
                #pragma unroll
                for (int r = 0; r < 4; ++r)
                    zb[(q * 4 + r) * PZ + ((ct * 16 + m) ^ (q << 4))] = bf16r(fmaxf(acc[r], 0.f));
            }
        }

        // ---- layer 1b: 64 -> 16 (h; h[0] is log_sigma) -----------------
        v4f hacc;
        {
            const v8s a10 = *(const v8s*)(zb + m * PZ + ((q * 8) ^ SWL(m)));
            const v8s a11 = *(const v8s*)(zb + m * PZ + ((32 + q * 8) ^ SWL(m)));
            v4f hv = {bb1b, bb1b, bb1b, bb1b};
            hv = MFMA16(a10, *(const v8s*)(sW1b + m * 72 + q * 8), hv);
            hv = MFMA16(a11, *(const v8s*)(sW1b + m * 72 + 32 + q * 8), hv);
            hacc = hv;
            #pragma unroll
            for (int r = 0; r < 4; ++r)
                zb[(q * 4 + r) * PZ + (m ^ (q << 4))] = bf16r(hv[r]);
        }

        // ---- posenc(dc) into z cols [16,43), zero pad [48,64) ----------
        {
            const float dd0 = dc[3*(j0+m)+0], dd1 = dc[3*(j0+m)+1], dd2 = dc[3*(j0+m)+2];
            v8s pk;
            #pragma unroll
            for (int jj = 0; jj < 8; ++jj) {
                const int k = 16 + q * 8 + jj;
                float v;
                if (k < 19) {
                    v = (k == 16) ? dd0 : ((k == 17) ? dd1 : dd2);
                } else if (k < 43) {
                    const int idx = k - 19;
                    const int e = idx / 6, w = idx - 6 * e;
                    const float base2 = (w == 0 || w == 3) ? dd0 : ((w == 1 || w == 4) ? dd1 : dd2);
                    const float s = (float)(1 << e) * base2;
                    v = (w < 3) ? __sinf(s) : __cosf(s);
                } else {
                    v = 0.f;
                }
                pk[jj] = bf16r(v);
            }
            *(v8s*)(zb + m * PZ + ((16 + q * 8) ^ SWL(m))) = pk;
            *(unsigned long long*)(zb + m * PZ + ((48 + q * 4) ^ SWL(m))) = 0ull;
        }

        // ---- layer 2a: z(43,pad64) -> 64, relu -------------------------
        {
            const v8s a20 = *(const v8s*)(zb + m * PZ + ((q * 8) ^ SWL(m)));
            const v8s a21 = *(const v8s*)(zb + m * PZ + ((32 + q * 8) ^ SWL(m)));
            #pragma unroll
            for (int ct = 0; ct < 4; ++ct) {
                const float bv = bb2a[ct];
                v4f acc = {bv, bv, bv, bv};
                acc = MFMA16(a20, *(const v8s*)(sW2a + (ct * 16 + m) * 72 + q * 8), acc);
                acc = MFMA16(a21, *(const v8s*)(sW2a + (ct * 16 + m) * 72 + 32 + q * 8), acc);
                #pragma unroll
                for (int r = 0; r < 4; ++r)
                    zb[(q * 4 + r) * PZ + ((ct * 16 + m) ^ (q << 4))] = bf16r(fmaxf(acc[r], 0.f));
            }
        }

        // ---- layer 2b: 64 -> 64, relu ----------------------------------
        {
            const v8s a20 = *(const v8s*)(zb + m * PZ + ((q * 8) ^ SWL(m)));
            const v8s a21 = *(const v8s*)(zb + m * PZ + ((32 + q * 8) ^ SWL(m)));
            #pragma unroll
            for (int ct = 0; ct < 4; ++ct) {
                const float bv = bb2b[ct];
                v4f acc = {bv, bv, bv, bv};
                acc = MFMA16(a20, *(const v8s*)(sW2b + (ct * 16 + m) * 72 + q * 8), acc);
                acc = MFMA16(a21, *(const v8s*)(sW2b + (ct * 16 + m) * 72 + 32 + q * 8), acc);
                #pragma unroll
                for (int r = 0; r < 4; ++r)
                    zb[(q * 4 + r) * PZ + ((ct * 16 + m) ^ (q << 4))] = bf16r(fmaxf(acc[r], 0.f));
            }
        }

        // ---- layer 2c: 64 -> 3, sigmoid, scatter store -----------------
        {
            const v8s a30 = *(const v8s*)(zb + m * PZ + ((q * 8) ^ SWL(m)));
            const v8s a31 = *(const v8s*)(zb + m * PZ + ((32 + q * 8) ^ SWL(m)));
            v4f cacc = {bb2c, bb2c, bb2c, bb2c};
            cacc = MFMA16(a30, *(const v8s*)(sW2c + m * 72 + q * 8), cacc);
            cacc = MFMA16(a31, *(const v8s*)(sW2c + m * 72 + 32 + q * 8), cacc);

            if (m < 3) {
                #pragma unroll
                for (int r = 0; r < 4; ++r) {
                    const unsigned pj = idxbuf[j0 + q * 4 + r];
                    if (pj < (unsigned)NPTS) {
                        const float cv = 1.0f / (1.0f + __expf(-cacc[r]));
                        out[3 * pj + m] = cv;
                    }
                }
            }
            if (m == 0) {
                #pragma unroll
                for (int r = 0; r < 4; ++r) {
                    const unsigned pj = idxbuf[j0 + q * 4 + r];
                    if (pj < (unsigned)NPTS)
                        out[3 * NPTS + pj] = __expf(hacc[r]);
                }
            }
        }
    }
}

// ---------------- fallback: fused VALU kernel (if ws too small) -------------
__global__ __launch_bounds__(256) void ngp_fused(
    const float* __restrict__ x, const float* __restrict__ d,
    const float* __restrict__ tables,
    const float* __restrict__ w1a, const float* __restrict__ b1a,
    const float* __restrict__ w1b, const float* __restrict__ b1b,
    const float* __restrict__ w2a, const float* __restrict__ b2a,
    const float* __restrict__ w2b, const float* __restrict__ b2b,
    const float* __restrict__ w2c, const float* __restrict__ b2c,
    float* __restrict__ out)
{
    const int i = blockIdx.x * 256 + threadIdx.x;
    if (i >= NPTS) return;
    const float xs0 = x[3*i+0] / 3.0f;
    const float xs1 = x[3*i+1] / 3.0f;
    const float xs2 = x[3*i+2] / 3.0f;
    const bool mask = (fabsf(xs0) < 0.5f) & (fabsf(xs1) < 0.5f) & (fabsf(xs2) < 0.5f);
    const float xu0 = xs0 + 0.5f, xu1 = xs1 + 0.5f, xu2 = xs2 + 0.5f;

    float feats[32];
    #pragma unroll
    for (int l = 0; l < 16; ++l) {
        const float n = NLf[l];
        const float p0 = xu0 * n, p1 = xu1 * n, p2 = xu2 * n;
        const float f0 = floorf(p0), f1 = floorf(p1), f2 = floorf(p2);
        const float fr0 = p0 - f0, fr1 = p1 - f1, fr2 = p2 - f2;
        const int vf0 = (int)f0, vf1 = (int)f1, vf2 = (int)f2;
        const int vc0 = (int)ceilf(p0), vc1 = (int)ceilf(p1), vc2 = (int)ceilf(p2);
        const float2* tbl = (const float2*)(tables + (size_t)l * (TSZ * 2));
        float a0 = 0.f, a1 = 0.f;
        #pragma unroll
        for (int k = 0; k < 8; ++k) {
            const unsigned vx = (unsigned)(((CEILX >> k) & 1) ? vc0 : vf0);
            const unsigned vy = (unsigned)(((CEILY >> k) & 1) ? vc1 : vf1);
            const unsigned vz = (unsigned)(((CEILZ >> k) & 1) ? vc2 : vf2);
            const unsigned h = (vx ^ (vy * 2654435761u) ^ (vz * 805459861u)) & TMASK;
            const float wx = (k & 1)        ? fr0 : 1.0f - fr0;
            const float wy = ((k >> 1) & 1) ? fr1 : 1.0f - fr1;
            const float wz = ((k >> 2) & 1) ? fr2 : 1.0f - fr2;
            const float wgt = wx * wy * wz;
            const float2 t = tbl[h];
            a0 = fmaf(wgt, t.x, a0);
            a1 = fmaf(wgt, t.y, a1);
        }
        feats[2*l] = a0; feats[2*l+1] = a1;
    }

    float h2v[16];
    #pragma unroll
    for (int j = 0; j < 16; ++j) h2v[j] = b1b[j];
    #pragma unroll
    for (int c = 0; c < 4; ++c) {
        float h1c[16];
        #pragma unroll
        for (int jj = 0; jj < 16; ++jj) h1c[jj] = b1a[16*c + jj];
        #pragma unroll
        for (int i2 = 0; i2 < 32; ++i2) {
            const float f = feats[i2];
            #pragma unroll
            for (int jj = 0; jj < 16; ++jj)
                h1c[jj] = fmaf(f, w1a[i2*64 + 16*c + jj], h1c[jj]);
        }
        #pragma unroll
        for (int jj = 0; jj < 16; ++jj) {
            const float f = fmaxf(h1c[jj], 0.f);
            #pragma unroll
            for (int t = 0; t < 16; ++t)
                h2v[t] = fmaf(f, w1b[(16*c + jj)*16 + t], h2v[t]);
        }
    }

    float z1[64];
    #pragma unroll
    for (int j = 0; j < 64; ++j) z1[j] = b2a[j];
    #pragma unroll
    for (int i2 = 0; i2 < 16; ++i2) {
        const float f = h2v[i2];
        #pragma unroll
        for (int j = 0; j < 64; ++j) z1[j] = fmaf(f, w2a[i2*64 + j], z1[j]);
    }
    const float d0 = d[3*i+0], d1 = d[3*i+1], d2 = d[3*i+2];
    {
        const float* r = w2a + 16*64;
        #pragma unroll
        for (int j = 0; j < 64; ++j) z1[j] = fmaf(d0, r[j], z1[j]);
        r = w2a + 17*64;
        #pragma unroll
        for (int j = 0; j < 64; ++j) z1[j] = fmaf(d1, r[j], z1[j]);
        r = w2a + 18*64;
        #pragma unroll
        for (int j = 0; j < 64; ++j) z1[j] = fmaf(d2, r[j], z1[j]);
    }
    #pragma unroll
    for (int e = 0; e < 4; ++e) {
        const float mm = (float)(1 << e);
        const float dv[3] = {d0, d1, d2};
        #pragma unroll
        for (int a = 0; a < 3; ++a) {
            const float sv = __sinf(mm * dv[a]);
            const float* rs = w2a + (19 + 6*e + a)*64;
            #pragma unroll
            for (int j = 0; j < 64; ++j) z1[j] = fmaf(sv, rs[j], z1[j]);
        }
        #pragma unroll
        for (int a = 0; a < 3; ++a) {
            const float cv = __cosf(mm * dv[a]);
            const float* rc = w2a + (19 + 6*e + 3 + a)*64;
            #pragma unroll
            for (int j = 0; j < 64; ++j) z1[j] = fmaf(cv, rc[j], z1[j]);
        }
    }
    #pragma unroll
    for (int j = 0; j < 64; ++j) z1[j] = fmaxf(z1[j], 0.f);

    float ca = b2c[0], cb = b2c[1], cc = b2c[2];
    #pragma unroll
    for (int jc = 0; jc < 64; jc += 16) {
        float acc[16];
        #pragma unroll
        for (int jj = 0; jj < 16; ++jj) acc[jj] = b2b[jc + jj];
        #pragma unroll
        for (int i2 = 0; i2 < 64; ++i2) {
            const float f = z1[i2];
            #pragma unroll
            for (int jj = 0; jj < 16; ++jj)
                acc[jj] = fmaf(f, w2b[i2*64 + jc + jj], acc[jj]);
        }
        #pragma unroll
        for (int jj = 0; jj < 16; ++jj) {
            const float v = fmaxf(acc[jj], 0.f);
            ca = fmaf(v, w2c[(jc + jj)*3 + 0], ca);
            cb = fmaf(v, w2c[(jc + jj)*3 + 1], cb);
            cc = fmaf(v, w2c[(jc + jj)*3 + 2], cc);
        }
    }

    float r = 1.0f / (1.0f + __expf(-ca));
    float g = 1.0f / (1.0f + __expf(-cb));
    float b = 1.0f / (1.0f + __expf(-cc));
    float sigma;
    if (mask) { sigma = __expf(h2v[0]); }
    else { r = 0.f; g = 0.f; b = 0.f; sigma = 0.f; }
    out[3*i + 0] = r;
    out[3*i + 1] = g;
    out[3*i + 2] = b;
    out[3*NPTS + i] = sigma;
}

extern "C" void kernel_launch(void* const* d_in, const int* in_sizes, int n_in,
                              void* d_out, int out_size, void* d_ws, size_t ws_size,
                              hipStream_t stream) {
    const float* x      = (const float*)d_in[0];
    const float* d      = (const float*)d_in[1];
    const float* tables = (const float*)d_in[2];
    const float* w1a    = (const float*)d_in[3];
    const float* b1a    = (const float*)d_in[4];
    const float* w1b    = (const float*)d_in[5];
    const float* b1b    = (const float*)d_in[6];
    const float* w2a    = (const float*)d_in[7];
    const float* b2a    = (const float*)d_in[8];
    const float* w2b    = (const float*)d_in[9];
    const float* b2b    = (const float*)d_in[10];
    const float* w2c    = (const float*)d_in[11];
    const float* b2c    = (const float*)d_in[12];
    float* out = (float*)d_out;

    // ws layout (u32 units): [0,16N) feats_pk; [16N,24N) tables_pk (fp8 2B/e);
    // [24N,25N) idxbuf; [25N] counter; [26N,29N) xc; [29N,32N) dc;
    // [32N, 32N+7040) wpk (bf16 weights)
    const size_t need = (size_t)33 * NPTS * 4;   // 66 MiB
    if (ws_size >= need) {
        unsigned* base      = (unsigned*)d_ws;
        unsigned* feats_pk  = base;
        unsigned* tables_pk = base + (size_t)16 * NPTS;
        unsigned* idxbuf    = base + (size_t)24 * NPTS;
        unsigned* cnt       = base + (size_t)25 * NPTS;
        float*    xc        = (float*)(base + (size_t)26 * NPTS);
        float*    dc        = (float*)(base + (size_t)29 * NPTS);
        unsigned short* wpk = (unsigned short*)(base + (size_t)32 * NPTS);

        dim3 gp(16 * TSZ / (256 * 2)), bp(256);
        hipLaunchKernelGGL(pack_tables, gp, bp, 0, stream,
                           (const float4*)tables, tables_pk, idxbuf, cnt);

        dim3 gw((WPK_TOT + 1023) / 1024), bw(1024);
        hipLaunchKernelGGL(ngp_packw, gw, bw, 0, stream,
                           w1a, w1b, w2a, w2b, w2c, wpk);

        dim3 gc(NPTS / 1024), bc(1024);
        hipLaunchKernelGGL(ngp_compact2, gc, bc, 0, stream,
                           x, d, idxbuf, xc, dc, cnt, out);

        dim3 gh(NPTS / 256, 16), bh(256);
        hipLaunchKernelGGL(ngp_hash6, gh, bh, 0, stream,
                           xc, (const unsigned short*)tables_pk, cnt, feats_pk);

        dim3 gm(NPTS / 512), bm(512);
        hipLaunchKernelGGL(ngp_mlp6, gm, bm, 0, stream,
                           dc, feats_pk, idxbuf, cnt, wpk,
                           b1a, b1b, b2a, b2b, b2c, out);
    } else {
        dim3 grid(NPTS / 256), block(256);
        hipLaunchKernelGGL(ngp_fused, grid, block, 0, stream,
                           x, d, tables, w1a, b1a, w1b, b1b,
                           w2a, b2a, w2b, b2b, w2c, b2c, out);
    }
}

// Round 8
// 255.140 us; speedup vs baseline: 1.4668x; 1.0388x over previous
//
#include <hip/hip_runtime.h>
#include <math.h>

#define NPTS 524288
#define HALF (NPTS / 2)
#define TSZ  524288
#define TMASK (TSZ - 1)
#define FP8SCALE 4096.0f
#define FP8INV   (1.0f / 4096.0f)

typedef __attribute__((ext_vector_type(8))) short v8s;   // 8 x bf16 (4 VGPR)
typedef __attribute__((ext_vector_type(4))) float v4f;   // MFMA C/D frag
typedef __attribute__((ext_vector_type(2))) float v2f;

#define MFMA16(a, b, c) __builtin_amdgcn_mfma_f32_16x16x32_bf16(a, b, c, 0, 0, 0)

__device__ __constant__ float NLf[16] = {
    16.f, 22.f, 30.f, 42.f, 58.f, 80.f, 110.f, 152.f,
    209.f, 288.f, 397.f, 547.f, 754.f, 1039.f, 1432.f, 1974.f
};

#define CEILX 0xE2
#define CEILY 0xD4
#define CEILZ 0xB8

__device__ __forceinline__ short bf16r(float v) {  // f32 -> bf16 RNE
    unsigned b = __float_as_uint(v);
    b += 0x7FFFu + ((b >> 16) & 1u);
    return (short)(b >> 16);
}
__device__ __forceinline__ unsigned packbf(float a, float b) {
    return (unsigned)(unsigned short)bf16r(a) | ((unsigned)(unsigned short)bf16r(b) << 16);
}
__device__ __forceinline__ unsigned cvtpk(float a, float b) {  // HW RNE pack (== packbf)
    unsigned r;
    asm("v_cvt_pk_bf16_f32 %0, %1, %2" : "=v"(r) : "v"(a), "v"(b));
    return r;
}
__device__ __forceinline__ unsigned sel4(uint4 t, unsigned i) {
    const unsigned ab = (i & 1u) ? t.y : t.x;
    const unsigned cd = (i & 1u) ? t.w : t.z;
    return (i & 2u) ? cd : ab;
}
__device__ __forceinline__ unsigned sel8(uint4 t, unsigned i) {  // pick ushort i of 8
    const unsigned w = sel4(t, i >> 1);
    return (i & 1u) ? (w >> 16) : (w & 0xFFFFu);
}

// ---- kernel 0: pack fp32 tables -> 2xfp8 e4m3 (2 B/entry), scale 4096 ------
__global__ __launch_bounds__(256) void pack_tables(
    const float4* __restrict__ tbl, unsigned* __restrict__ out,
    unsigned* __restrict__ idxbuf, unsigned* __restrict__ cnt)
{
    const int idx = blockIdx.x * 256 + threadIdx.x;   // handles 2 entries
    const float4 t = tbl[idx];
    const unsigned lo = (unsigned)__builtin_amdgcn_cvt_pk_fp8_f32(
                            t.x * FP8SCALE, t.y * FP8SCALE, 0, false) & 0xFFFFu;
    const unsigned hi = (unsigned)__builtin_amdgcn_cvt_pk_fp8_f32(
                            t.z * FP8SCALE, t.w * FP8SCALE, 0, false) & 0xFFFFu;
    out[idx] = lo | (hi << 16);
    if (idx < NPTS) idxbuf[idx] = 0xFFFFFFFFu;        // sentinel for tail tiles
    if (idx == 0) cnt[0] = 0u;
}

// ---- kernel 0a: pre-pack MLP weights into exact LDS layouts (bf16) ---------
#define W1A_OFF 0        // 64 x 40
#define W1B_OFF 2560     // 16 x 72
#define W2A_OFF 3712     // 64 x 72
#define W2B_OFF 8320     // 64 x 72
#define W2C_OFF 12928    // 16 x 72
#define WPK_TOT 14080    // shorts (28160 B = 1760 uint4)

__global__ __launch_bounds__(1024) void ngp_packw(
    const float* __restrict__ w1a, const float* __restrict__ w1b,
    const float* __restrict__ w2a, const float* __restrict__ w2b,
    const float* __restrict__ w2c, unsigned short* __restrict__ wpk)
{
    const int s = blockIdx.x * 1024 + threadIdx.x;
    if (s >= WPK_TOT) return;
    float v = 0.f;
    if (s < W1B_OFF) {                     // sW1a: n(64) x k(40), k<32 live
        const int r = s - W1A_OFF, n = r / 40, k = r % 40;
        v = (k < 32) ? w1a[k * 64 + n] : 0.f;
    } else if (s < W2A_OFF) {              // sW1b: n(16) x k(72), k<64 live
        const int r = s - W1B_OFF, n = r / 72, k = r % 72;
        v = (k < 64) ? w1b[k * 16 + n] : 0.f;
    } else if (s < W2B_OFF) {              // sW2a: n(64) x k(72), k<43 live
        const int r = s - W2A_OFF, n = r / 72, k = r % 72;
        v = (k < 43) ? w2a[k * 64 + n] : 0.f;
    } else if (s < W2C_OFF) {              // sW2b: n(64) x k(72), k<64 live
        const int r = s - W2B_OFF, n = r / 72, k = r % 72;
        v = (k < 64) ? w2b[k * 64 + n] : 0.f;
    } else {                               // sW2c: n(16) x k(72), n<3,k<64 live
        const int r = s - W2C_OFF, n = r / 72, k = r % 72;
        v = (k < 64 && n < 3) ? w2c[k * 3 + n] : 0.f;
    }
    wpk[s] = (unsigned short)bf16r(v);
}

// ---- kernel 0b: mask + stream compaction (block-aggregated atomic) ---------
__global__ __launch_bounds__(1024) void ngp_compact2(
    const float* __restrict__ x, const float* __restrict__ d,
    unsigned* __restrict__ idxbuf, float* __restrict__ xc,
    float* __restrict__ dc, unsigned* __restrict__ cnt,
    float* __restrict__ out)
{
    __shared__ unsigned sWCnt[16];
    __shared__ unsigned sBase;

    const int tid  = threadIdx.x;
    const int wv   = tid >> 6, lane = tid & 63;
    const int i    = blockIdx.x * 1024 + tid;

    const float x0 = x[3*i+0], x1 = x[3*i+1], x2 = x[3*i+2];
    const float xs0 = x0 / 3.0f, xs1 = x1 / 3.0f, xs2 = x2 / 3.0f;
    const bool act = (fabsf(xs0) < 0.5f) && (fabsf(xs1) < 0.5f) && (fabsf(xs2) < 0.5f);
    if (!act) {
        out[3*i+0] = 0.f; out[3*i+1] = 0.f; out[3*i+2] = 0.f;
        out[3*NPTS + i] = 0.f;
    }
    const unsigned long long mb = __ballot(act);
    if (lane == 0) sWCnt[wv] = (unsigned)__popcll(mb);
    __syncthreads();
    if (tid == 0) {
        unsigned tot = 0;
        #pragma unroll
        for (int w = 0; w < 16; ++w) tot += sWCnt[w];
        sBase = atomicAdd(cnt, tot);
    }
    __syncthreads();
    if (act) {
        unsigned off = sBase;
        for (int w = 0; w < wv; ++w) off += sWCnt[w];
        off += (unsigned)__popcll(mb & ((1ull << lane) - 1ull));
        idxbuf[off] = (unsigned)i;
        xc[3*off+0] = x0; xc[3*off+1] = x1; xc[3*off+2] = x2;
        dc[3*off+0] = d[3*i+0]; dc[3*off+1] = d[3*i+1]; dc[3*off+2] = d[3*i+2];
    }
}

// ---- kernel 1: hash gather, fp8 tables (R6 verified: 94us) -----------------
__global__ __launch_bounds__(256) void ngp_hash6(
    const float* __restrict__ xc, const unsigned short* __restrict__ tables_pk,
    const unsigned* __restrict__ cnt, unsigned* __restrict__ feats_pk)
{
    __shared__ float sX[768];
    const int NC = (int)cnt[0];
    if (blockIdx.x * 256 >= NC) return;       // compacted tail: nothing to do

    const int tid = threadIdx.x;
    const int l = blockIdx.y;
    const float n = NLf[l];
    const unsigned short* tbl = tables_pk + (size_t)l * TSZ;

    for (int r = tid; r < 768; r += 256)
        sX[r] = xc[(size_t)blockIdx.x * 768 + r];
    __syncthreads();

    const int j = blockIdx.x * 256 + tid;     // compact index (>=NC rows: unused)
    const float xu0 = sX[tid * 3 + 0] / 3.0f + 0.5f;
    const float xu1 = sX[tid * 3 + 1] / 3.0f + 0.5f;
    const float xu2 = sX[tid * 3 + 2] / 3.0f + 0.5f;

    const float p0 = xu0 * n, p1 = xu1 * n, p2 = xu2 * n;
    const float f0 = floorf(p0), f1 = floorf(p1), f2 = floorf(p2);
    const float fr0 = p0 - f0, fr1 = p1 - f1, fr2 = p2 - f2;
    const float g0 = 1.f - fr0, g1 = 1.f - fr1, g2 = 1.f - fr2;
    const unsigned uvf0 = (unsigned)(int)f0;
    const unsigned uvc0 = (unsigned)(int)ceilf(p0);
    const unsigned syf = (unsigned)(int)f1 * 2654435761u;
    const unsigned syc = (unsigned)(int)ceilf(p1) * 2654435761u;
    const unsigned szf = (unsigned)(int)f2 * 805459861u;
    const unsigned szc = (unsigned)(int)ceilf(p2) * 805459861u;

    const float w0 = g0 * g1 * g2,  w1 = fr0 * g1 * g2;
    const float w2 = g0 * fr1 * g2, w6 = g0 * fr1 * fr2;
    const float w3 = fr0 * fr1 * g2, w5 = fr0 * g1 * fr2;
    const float w4 = g0 * g1 * fr2, w7 = fr0 * fr1 * fr2;

    const unsigned Ss[4] = { syf ^ szf, syc ^ szf, syf ^ szc, syc ^ szc };
    const float wf[4] = { w0, w2, w3, w4 };
    const float wc[4] = { w1, w6, w5, w7 };

    float a0 = 0.f, a1 = 0.f;
    #pragma unroll
    for (int pr = 0; pr < 4; ++pr) {
        const unsigned hf = (Ss[pr] ^ uvf0) & TMASK;
        const unsigned hc = (Ss[pr] ^ uvc0) & TMASK;
        const unsigned diff = hf ^ hc;
        const uint4 tv = *(const uint4*)(tbl + (hf & ~7u));   // 8 entries
        const unsigned ef = sel8(tv, hf & 7u);
        unsigned ec;
        if (diff <= 7u) ec = sel8(tv, hc & 7u);
        else            ec = (unsigned)tbl[hc];
        const v2f ff = __builtin_amdgcn_cvt_pk_f32_fp8((int)ef, false);
        const v2f fc = __builtin_amdgcn_cvt_pk_f32_fp8((int)ec, false);
        a0 = fmaf(wf[pr], ff.x, a0);
        a1 = fmaf(wf[pr], ff.y, a1);
        a0 = fmaf(wc[pr], fc.x, a0);
        a1 = fmaf(wc[pr], fc.y, a1);
    }
    a0 *= FP8INV;  // exact pow2 unscale
    a1 *= FP8INV;
    feats_pk[(size_t)l * NPTS + j] = packbf(a0, a1);
}

// ---- kernel 2: MFMA MLP, swapped-operand (transposed-D) form ---------------
// R8: MFMA A/B fragment layouts are symmetric (both indexed by lane&15,
// k=(lane>>4)*8+j), so MFMA16(W,Z,acc) computes the layer output TRANSPOSED
// (D[feat=q*4+r][point=m]) with byte-identical operand reads. Epilogue per ct
// becomes 2 cvt_pk_bf16 + one 8B row-local ds_write (was 4 bf16r + 4 scalar
// b16 column-scattered writes + XOR swizzle). Same math, same rounding.
#define PZ 72   // z-buffer pitch in shorts (144 B, 16B-aligned)

__global__ __launch_bounds__(512) void ngp_mlp7(
    const float* __restrict__ dc,
    const unsigned* __restrict__ feats_pk, const unsigned* __restrict__ idxbuf,
    const unsigned* __restrict__ cnt, const unsigned short* __restrict__ wpk,
    const float* __restrict__ b1a, const float* __restrict__ b1b,
    const float* __restrict__ b2a, const float* __restrict__ b2b,
    const float* __restrict__ b2c,
    float* __restrict__ out)
{
    __shared__ short sW[WPK_TOT];
    __shared__ short sZ[8 * 16 * PZ];

    const int NC = (int)cnt[0];
    if (blockIdx.x * 512 >= NC) return;       // whole block beyond compact set

    const int tid = threadIdx.x;
    for (int i = tid; i < WPK_TOT / 8; i += 512)
        ((uint4*)sW)[i] = ((const uint4*)wpk)[i];
    __syncthreads();

    const short* sW1a = sW + W1A_OFF;
    const short* sW1b = sW + W1B_OFF;
    const short* sW2a = sW + W2A_OFF;
    const short* sW2b = sW + W2B_OFF;
    const short* sW2c = sW + W2C_OFF;

    const int wave = tid >> 6, lane = tid & 63;
    const int m = lane & 15, q = lane >> 4;
    short* zb = &sZ[wave * 16 * PZ];

    // per-reg biases: reg r holds feature q*4+r (transposed-D layout)
    v4f bb1a[4], bb2a[4], bb2b[4];
    #pragma unroll
    for (int ct = 0; ct < 4; ++ct) {
        bb1a[ct] = *(const v4f*)(b1a + ct * 16 + q * 4);
        bb2a[ct] = *(const v4f*)(b2a + ct * 16 + q * 4);
        bb2b[ct] = *(const v4f*)(b2b + ct * 16 + q * 4);
    }
    const v4f bb1b4 = *(const v4f*)(b1b + q * 4);
    v4f bb2c4 = {0.f, 0.f, 0.f, 0.f};
    if (q == 0) { bb2c4[0] = b2c[0]; bb2c4[1] = b2c[1]; bb2c4[2] = b2c[2]; }

    const int base = (blockIdx.x * 8 + wave) * 64;   // 4 consecutive tiles

    for (int t = 0; t < 4; ++t) {
        const int j0 = base + t * 16;
        if (j0 >= NC) break;

        // ---- feats -> z cols [0,32) ------------------------------------
        #pragma unroll
        for (int it = 0; it < 4; ++it) {
            const int l = it * 4 + q;
            *(unsigned*)(zb + m * PZ + 2 * l) =
                feats_pk[(size_t)l * NPTS + j0 + m];
        }

        // ---- layer 1a: feats(32) -> 64, relu (swapped MFMA) ------------
        {
            const v8s z0 = *(const v8s*)(zb + m * PZ + q * 8);
            #pragma unroll
            for (int ct = 0; ct < 4; ++ct) {
                v4f acc = bb1a[ct];
                acc = MFMA16(*(const v8s*)(sW1a + (ct * 16 + m) * 40 + q * 8), z0, acc);
                const unsigned lo = cvtpk(fmaxf(acc[0], 0.f), fmaxf(acc[1], 0.f));
                const unsigned hi = cvtpk(fmaxf(acc[2], 0.f), fmaxf(acc[3], 0.f));
                *(uint2*)(zb + m * PZ + ct * 16 + q * 4) = make_uint2(lo, hi);
            }
        }

        // ---- layer 1b: 64 -> 16 (h; h[0] is log_sigma) -----------------
        {
            const v8s z0 = *(const v8s*)(zb + m * PZ + q * 8);
            const v8s z1 = *(const v8s*)(zb + m * PZ + 32 + q * 8);
            v4f hv = bb1b4;
            hv = MFMA16(*(const v8s*)(sW1b + m * 72 + q * 8), z0, hv);
            hv = MFMA16(*(const v8s*)(sW1b + m * 72 + 32 + q * 8), z1, hv);
            if (q == 0) {                     // reg 0 = feat 0 = log_sigma of point m
                const unsigned pj = idxbuf[j0 + m];
                if (pj < (unsigned)NPTS)
                    out[3 * NPTS + pj] = __expf(hv[0]);
            }
            const unsigned lo = cvtpk(hv[0], hv[1]);
            const unsigned hi = cvtpk(hv[2], hv[3]);
            *(uint2*)(zb + m * PZ + q * 4) = make_uint2(lo, hi);
        }

        // ---- posenc(dc) into z cols [16,43), zero pad [48,64) ----------
        {
            const float dd0 = dc[3*(j0+m)+0], dd1 = dc[3*(j0+m)+1], dd2 = dc[3*(j0+m)+2];
            float pv[8];
            #pragma unroll
            for (int jj = 0; jj < 8; ++jj) {
                const int k = 16 + q * 8 + jj;
                float v;
                if (k < 19) {
                    v = (k == 16) ? dd0 : ((k == 17) ? dd1 : dd2);
                } else if (k < 43) {
                    const int idx = k - 19;
                    const int e = idx / 6, w = idx - 6 * e;
                    const float base2 = (w == 0 || w == 3) ? dd0 : ((w == 1 || w == 4) ? dd1 : dd2);
                    const float s = (float)(1 << e) * base2;
                    v = (w < 3) ? __sinf(s) : __cosf(s);
                } else {
                    v = 0.f;
                }
                pv[jj] = v;
            }
            const uint4 pk4 = make_uint4(cvtpk(pv[0], pv[1]), cvtpk(pv[2], pv[3]),
                                         cvtpk(pv[4], pv[5]), cvtpk(pv[6], pv[7]));
            *(uint4*)(zb + m * PZ + 16 + q * 8) = pk4;
            *(unsigned long long*)(zb + m * PZ + 48 + q * 4) = 0ull;
        }

        // ---- layer 2a: z(43,pad64) -> 64, relu -------------------------
        {
            const v8s z0 = *(const v8s*)(zb + m * PZ + q * 8);
            const v8s z1 = *(const v8s*)(zb + m * PZ + 32 + q * 8);
            #pragma unroll
            for (int ct = 0; ct < 4; ++ct) {
                v4f acc = bb2a[ct];
                acc = MFMA16(*(const v8s*)(sW2a + (ct * 16 + m) * 72 + q * 8), z0, acc);
                acc = MFMA16(*(const v8s*)(sW2a + (ct * 16 + m) * 72 + 32 + q * 8), z1, acc);
                const unsigned lo = cvtpk(fmaxf(acc[0], 0.f), fmaxf(acc[1], 0.f));
                const unsigned hi = cvtpk(fmaxf(acc[2], 0.f), fmaxf(acc[3], 0.f));
                *(uint2*)(zb + m * PZ + ct * 16 + q * 4) = make_uint2(lo, hi);
            }
        }

        // ---- layer 2b: 64 -> 64, relu ----------------------------------
        {
            const v8s z0 = *(const v8s*)(zb + m * PZ + q * 8);
            const v8s z1 = *(const v8s*)(zb + m * PZ + 32 + q * 8);
            #pragma unroll
            for (int ct = 0; ct < 4; ++ct) {
                v4f acc = bb2b[ct];
                acc = MFMA16(*(const v8s*)(sW2b + (ct * 16 + m) * 72 + q * 8), z0, acc);
                acc = MFMA16(*(const v8s*)(sW2b + (ct * 16 + m) * 72 + 32 + q * 8), z1, acc);
                const unsigned lo = cvtpk(fmaxf(acc[0], 0.f), fmaxf(acc[1], 0.f));
                const unsigned hi = cvtpk(fmaxf(acc[2], 0.f), fmaxf(acc[3], 0.f));
                *(uint2*)(zb + m * PZ + ct * 16 + q * 4) = make_uint2(lo, hi);
            }
        }

        // ---- layer 2c: 64 -> 3, sigmoid, contiguous store --------------
        {
            const v8s z0 = *(const v8s*)(zb + m * PZ + q * 8);
            const v8s z1 = *(const v8s*)(zb + m * PZ + 32 + q * 8);
            v4f cacc = bb2c4;
            cacc = MFMA16(*(const v8s*)(sW2c + m * 72 + q * 8), z0, cacc);
            cacc = MFMA16(*(const v8s*)(sW2c + m * 72 + 32 + q * 8), z1, cacc);

            if (q == 0) {                     // regs 0..2 = color of point m
                const unsigned pj = idxbuf[j0 + m];
                if (pj < (unsigned)NPTS) {
                    out[3 * pj + 0] = 1.0f / (1.0f + __expf(-cacc[0]));
                    out[3 * pj + 1] = 1.0f / (1.0f + __expf(-cacc[1]));
                    out[3 * pj + 2] = 1.0f / (1.0f + __expf(-cacc[2]));
                }
            }
        }
    }
}

// ---------------- fallback: fused VALU kernel (if ws too small) -------------
__global__ __launch_bounds__(256) void ngp_fused(
    const float* __restrict__ x, const float* __restrict__ d,
    const float* __restrict__ tables,
    const float* __restrict__ w1a, const float* __restrict__ b1a,
    const float* __restrict__ w1b, const float* __restrict__ b1b,
    const float* __restrict__ w2a, const float* __restrict__ b2a,
    const float* __restrict__ w2b, const float* __restrict__ b2b,
    const float* __restrict__ w2c, const float* __restrict__ b2c,
    float* __restrict__ out)
{
    const int i = blockIdx.x * 256 + threadIdx.x;
    if (i >= NPTS) return;
    const float xs0 = x[3*i+0] / 3.0f;
    const float xs1 = x[3*i+1] / 3.0f;
    const float xs2 = x[3*i+2] / 3.0f;
    const bool mask = (fabsf(xs0) < 0.5f) & (fabsf(xs1) < 0.5f) & (fabsf(xs2) < 0.5f);
    const float xu0 = xs0 + 0.5f, xu1 = xs1 + 0.5f, xu2 = xs2 + 0.5f;

    float feats[32];
    #pragma unroll
    for (int l = 0; l < 16; ++l) {
        const float n = NLf[l];
        const float p0 = xu0 * n, p1 = xu1 * n, p2 = xu2 * n;
        const float f0 = floorf(p0), f1 = floorf(p1), f2 = floorf(p2);
        const float fr0 = p0 - f0, fr1 = p1 - f1, fr2 = p2 - f2;
        const int vf0 = (int)f0, vf1 = (int)f1, vf2 = (int)f2;
        const int vc0 = (int)ceilf(p0), vc1 = (int)ceilf(p1), vc2 = (int)ceilf(p2);
        const float2* tbl = (const float2*)(tables + (size_t)l * (TSZ * 2));
        float a0 = 0.f, a1 = 0.f;
        #pragma unroll
        for (int k = 0; k < 8; ++k) {
            const unsigned vx = (unsigned)(((CEILX >> k) & 1) ? vc0 : vf0);
            const unsigned vy = (unsigned)(((CEILY >> k) & 1) ? vc1 : vf1);
            const unsigned vz = (unsigned)(((CEILZ >> k) & 1) ? vc2 : vf2);
            const unsigned h = (vx ^ (vy * 2654435761u) ^ (vz * 805459861u)) & TMASK;
            const float wx = (k & 1)        ? fr0 : 1.0f - fr0;
            const float wy = ((k >> 1) & 1) ? fr1 : 1.0f - fr1;
            const float wz = ((k >> 2) & 1) ? fr2 : 1.0f - fr2;
            const float wgt = wx * wy * wz;
            const float2 t = tbl[h];
            a0 = fmaf(wgt, t.x, a0);
            a1 = fmaf(wgt, t.y, a1);
        }
        feats[2*l] = a0; feats[2*l+1] = a1;
    }

    float h2v[16];
    #pragma unroll
    for (int j = 0; j < 16; ++j) h2v[j] = b1b[j];
    #pragma unroll
    for (int c = 0; c < 4; ++c) {
        float h1c[16];
        #pragma unroll
        for (int jj = 0; jj < 16; ++jj) h1c[jj] = b1a[16*c + jj];
        #pragma unroll
        for (int i2 = 0; i2 < 32; ++i2) {
            const float f = feats[i2];
            #pragma unroll
            for (int jj = 0; jj < 16; ++jj)
                h1c[jj] = fmaf(f, w1a[i2*64 + 16*c + jj], h1c[jj]);
        }
        #pragma unroll
        for (int jj = 0; jj < 16; ++jj) {
            const float f = fmaxf(h1c[jj], 0.f);
            #pragma unroll
            for (int t = 0; t < 16; ++t)
                h2v[t] = fmaf(f, w1b[(16*c + jj)*16 + t], h2v[t]);
        }
    }

    float z1[64];
    #pragma unroll
    for (int j = 0; j < 64; ++j) z1[j] = b2a[j];
    #pragma unroll
    for (int i2 = 0; i2 < 16; ++i2) {
        const float f = h2v[i2];
        #pragma unroll
        for (int j = 0; j < 64; ++j) z1[j] = fmaf(f, w2a[i2*64 + j], z1[j]);
    }
    const float d0 = d[3*i+0], d1 = d[3*i+1], d2 = d[3*i+2];
    {
        const float* r = w2a + 16*64;
        #pragma unroll
        for (int j = 0; j < 64; ++j) z1[j] = fmaf(d0, r[j], z1[j]);
        r = w2a + 17*64;
        #pragma unroll
        for (int j = 0; j < 64; ++j) z1[j] = fmaf(d1, r[j], z1[j]);
        r = w2a + 18*64;
        #pragma unroll
        for (int j = 0; j < 64; ++j) z1[j] = fmaf(d2, r[j], z1[j]);
    }
    #pragma unroll
    for (int e = 0; e < 4; ++e) {
        const float mm = (float)(1 << e);
        const float dv[3] = {d0, d1, d2};
        #pragma unroll
        for (int a = 0; a < 3; ++a) {
            const float sv = __sinf(mm * dv[a]);
            const float* rs = w2a + (19 + 6*e + a)*64;
            #pragma unroll
            for (int j = 0; j < 64; ++j) z1[j] = fmaf(sv, rs[j], z1[j]);
        }
        #pragma unroll
        for (int a = 0; a < 3; ++a) {
            const float cv = __cosf(mm * dv[a]);
            const float* rc = w2a + (19 + 6*e + 3 + a)*64;
            #pragma unroll
            for (int j = 0; j < 64; ++j) z1[j] = fmaf(cv, rc[j], z1[j]);
        }
    }
    #pragma unroll
    for (int j = 0; j < 64; ++j) z1[j] = fmaxf(z1[j], 0.f);

    float ca = b2c[0], cb = b2c[1], cc = b2c[2];
    #pragma unroll
    for (int jc = 0; jc < 64; jc += 16) {
        float acc[16];
        #pragma unroll
        for (int jj = 0; jj < 16; ++jj) acc[jj] = b2b[jc + jj];
        #pragma unroll
        for (int i2 = 0; i2 < 64; ++i2) {
            const float f = z1[i2];
            #pragma unroll
            for (int jj = 0; jj < 16; ++jj)
                acc[jj] = fmaf(f, w2b[i2*64 + jc + jj], acc[jj]);
        }
        #pragma unroll
        for (int jj = 0; jj < 16; ++jj) {
            const float v = fmaxf(acc[jj], 0.f);
            ca = fmaf(v, w2c[(jc + jj)*3 + 0], ca);
            cb = fmaf(v, w2c[(jc + jj)*3 + 1], cb);
            cc = fmaf(v, w2c[(jc + jj)*3 + 2], cc);
        }
    }

    float r = 1.0f / (1.0f + __expf(-ca));
    float g = 1.0f / (1.0f + __expf(-cb));
    float b = 1.0f / (1.0f + __expf(-cc));
    float sigma;
    if (mask) { sigma = __expf(h2v[0]); }
    else { r = 0.f; g = 0.f; b = 0.f; sigma = 0.f; }
    out[3*i + 0] = r;
    out[3*i + 1] = g;
    out[3*i + 2] = b;
    out[3*NPTS + i] = sigma;
}

extern "C" void kernel_launch(void* const* d_in, const int* in_sizes, int n_in,
                              void* d_out, int out_size, void* d_ws, size_t ws_size,
                              hipStream_t stream) {
    const float* x      = (const float*)d_in[0];
    const float* d      = (const float*)d_in[1];
    const float* tables = (const float*)d_in[2];
    const float* w1a    = (const float*)d_in[3];
    const float* b1a    = (const float*)d_in[4];
    const float* w1b    = (const float*)d_in[5];
    const float* b1b    = (const float*)d_in[6];
    const float* w2a    = (const float*)d_in[7];
    const float* b2a    = (const float*)d_in[8];
    const float* w2b    = (const float*)d_in[9];
    const float* b2b    = (const float*)d_in[10];
    const float* w2c    = (const float*)d_in[11];
    const float* b2c    = (const float*)d_in[12];
    float* out = (float*)d_out;

    // ws layout (u32 units): [0,16N) feats_pk; [16N,24N) tables_pk (fp8 2B/e);
    // [24N,25N) idxbuf; [25N] counter; [26N,29N) xc; [29N,32N) dc;
    // [32N, 32N+7040) wpk (bf16 weights)
    const size_t need = (size_t)33 * NPTS * 4;   // 66 MiB
    if (ws_size >= need) {
        unsigned* base      = (unsigned*)d_ws;
        unsigned* feats_pk  = base;
        unsigned* tables_pk = base + (size_t)16 * NPTS;
        unsigned* idxbuf    = base + (size_t)24 * NPTS;
        unsigned* cnt       = base + (size_t)25 * NPTS;
        float*    xc        = (float*)(base + (size_t)26 * NPTS);
        float*    dc        = (float*)(base + (size_t)29 * NPTS);
        unsigned short* wpk = (unsigned short*)(base + (size_t)32 * NPTS);

        dim3 gp(16 * TSZ / (256 * 2)), bp(256);
        hipLaunchKernelGGL(pack_tables, gp, bp, 0, stream,
                           (const float4*)tables, tables_pk, idxbuf, cnt);

        dim3 gw((WPK_TOT + 1023) / 1024), bw(1024);
        hipLaunchKernelGGL(ngp_packw, gw, bw, 0, stream,
                           w1a, w1b, w2a, w2b, w2c, wpk);

        dim3 gc(NPTS / 1024), bc(1024);
        hipLaunchKernelGGL(ngp_compact2, gc, bc, 0, stream,
                           x, d, idxbuf, xc, dc, cnt, out);

        dim3 gh(NPTS / 256, 16), bh(256);
        hipLaunchKernelGGL(ngp_hash6, gh, bh, 0, stream,
                           xc, (const unsigned short*)tables_pk, cnt, feats_pk);

        dim3 gm(NPTS / 512), bm(512);
        hipLaunchKernelGGL(ngp_mlp7, gm, bm, 0, stream,
                           dc, feats_pk, idxbuf, cnt, wpk,
                           b1a, b1b, b2a, b2b, b2c, out);
    } else {
        dim3 grid(NPTS / 256), block(256);
        hipLaunchKernelGGL(ngp_fused, grid, block, 0, stream,
                           x, d, tables, w1a, b1a, w1b, b1b,
                           w2a, b2a, w2b, b2b, w2c, b2c, out);
    }
}

// Round 10
// 248.569 us; speedup vs baseline: 1.5056x; 1.0264x over previous
//
#include <hip/hip_runtime.h>
#include <math.h>

#define NPTS 524288
#define HALF (NPTS / 2)
#define TSZ  524288
#define TMASK (TSZ - 1)
#define FP8SCALE 4096.0f
#define FP8INV   (1.0f / 4096.0f)

typedef __attribute__((ext_vector_type(8))) short v8s;   // 8 x bf16 (4 VGPR)
typedef __attribute__((ext_vector_type(4))) float v4f;   // MFMA C/D frag
typedef __attribute__((ext_vector_type(2))) float v2f;

#define MFMA16(a, b, c) __builtin_amdgcn_mfma_f32_16x16x32_bf16(a, b, c, 0, 0, 0)

__device__ __constant__ float NLf[16] = {
    16.f, 22.f, 30.f, 42.f, 58.f, 80.f, 110.f, 152.f,
    209.f, 288.f, 397.f, 547.f, 754.f, 1039.f, 1432.f, 1974.f
};

#define CEILX 0xE2
#define CEILY 0xD4
#define CEILZ 0xB8

__device__ __forceinline__ short bf16r(float v) {  // f32 -> bf16 RNE
    unsigned b = __float_as_uint(v);
    b += 0x7FFFu + ((b >> 16) & 1u);
    return (short)(b >> 16);
}
__device__ __forceinline__ unsigned packbf(float a, float b) {
    return (unsigned)(unsigned short)bf16r(a) | ((unsigned)(unsigned short)bf16r(b) << 16);
}
__device__ __forceinline__ unsigned cvtpk(float a, float b) {  // HW RNE pack (== packbf)
    unsigned r;
    asm("v_cvt_pk_bf16_f32 %0, %1, %2" : "=v"(r) : "v"(a), "v"(b));
    return r;
}
__device__ __forceinline__ unsigned sel4(uint4 t, unsigned i) {
    const unsigned ab = (i & 1u) ? t.y : t.x;
    const unsigned cd = (i & 1u) ? t.w : t.z;
    return (i & 2u) ? cd : ab;
}
__device__ __forceinline__ unsigned sel8(uint4 t, unsigned i) {  // pick ushort i of 8
    const unsigned w = sel4(t, i >> 1);
    return (i & 1u) ? (w >> 16) : (w & 0xFFFFu);
}

#define W1A_OFF 0        // 64 x 40
#define W1B_OFF 2560     // 16 x 72
#define W2A_OFF 3712     // 64 x 72
#define W2B_OFF 8320     // 64 x 72
#define W2C_OFF 12928    // 16 x 72
#define WPK_TOT 14080    // shorts (28160 B = 1760 uint4)

// ---- kernel 0: merged prologue ---------------------------------------------
// R10 fix: R9 raced — in-kernel idxbuf sentinel writes (indexed by point id)
// vs cross-block compact writes (indexed by compact slot) are unordered; a
// late sentinel could overwrite a valid compact entry -> dropped points
// (absmax 0.51). Sentinel init moved to hipMemsetAsync(idxbuf, 0xFF) before
// this kernel (stream-ordered). No other changes.
__global__ __launch_bounds__(1024) void ngp_prologue(
    const float* __restrict__ x, const float* __restrict__ d,
    const float4* __restrict__ tbl,
    const float* __restrict__ w1a, const float* __restrict__ w1b,
    const float* __restrict__ w2a, const float* __restrict__ w2b,
    const float* __restrict__ w2c,
    unsigned* __restrict__ tables_pk, unsigned short* __restrict__ wpk,
    unsigned* __restrict__ idxbuf, float* __restrict__ xc,
    float* __restrict__ dc, unsigned* __restrict__ cnt,
    float* __restrict__ out)
{
    __shared__ unsigned sWCnt[16];
    __shared__ unsigned sBase;

    const int tid  = threadIdx.x;
    const int wv   = tid >> 6, lane = tid & 63;
    const int i    = blockIdx.x * 1024 + tid;   // 512*1024 == NPTS exactly

    // --- fp8 table pack: 8 uint32 outputs per thread (grid-stride) ---------
    #pragma unroll
    for (int k = 0; k < 8; ++k) {
        const int idx = i + k * NPTS;           // < 16*TSZ/2 = 8*NPTS
        const float4 t = tbl[idx];
        const unsigned lo = (unsigned)__builtin_amdgcn_cvt_pk_fp8_f32(
                                t.x * FP8SCALE, t.y * FP8SCALE, 0, false) & 0xFFFFu;
        const unsigned hi = (unsigned)__builtin_amdgcn_cvt_pk_fp8_f32(
                                t.z * FP8SCALE, t.w * FP8SCALE, 0, false) & 0xFFFFu;
        tables_pk[idx] = lo | (hi << 16);
    }

    // --- weight pack (first 14080 threads) ---------------------------------
    if (i < WPK_TOT) {
        const int s = i;
        float v = 0.f;
        if (s < W1B_OFF) {
            const int r = s - W1A_OFF, n = r / 40, k = r % 40;
            v = (k < 32) ? w1a[k * 64 + n] : 0.f;
        } else if (s < W2A_OFF) {
            const int r = s - W1B_OFF, n = r / 72, k = r % 72;
            v = (k < 64) ? w1b[k * 16 + n] : 0.f;
        } else if (s < W2B_OFF) {
            const int r = s - W2A_OFF, n = r / 72, k = r % 72;
            v = (k < 43) ? w2a[k * 64 + n] : 0.f;
        } else if (s < W2C_OFF) {
            const int r = s - W2B_OFF, n = r / 72, k = r % 72;
            v = (k < 64) ? w2b[k * 64 + n] : 0.f;
        } else {
            const int r = s - W2C_OFF, n = r / 72, k = r % 72;
            v = (k < 64 && n < 3) ? w2c[k * 3 + n] : 0.f;
        }
        wpk[s] = (unsigned short)bf16r(v);
    }

    // --- mask + compaction (block-aggregated atomic, R5-verified) ----------
    const float x0 = x[3*i+0], x1 = x[3*i+1], x2 = x[3*i+2];
    const float xs0 = x0 / 3.0f, xs1 = x1 / 3.0f, xs2 = x2 / 3.0f;
    const bool act = (fabsf(xs0) < 0.5f) && (fabsf(xs1) < 0.5f) && (fabsf(xs2) < 0.5f);
    if (!act) {
        out[3*i+0] = 0.f; out[3*i+1] = 0.f; out[3*i+2] = 0.f;
        out[3*NPTS + i] = 0.f;
    }
    const unsigned long long mb = __ballot(act);
    if (lane == 0) sWCnt[wv] = (unsigned)__popcll(mb);
    __syncthreads();
    if (tid == 0) {
        unsigned tot = 0;
        #pragma unroll
        for (int w = 0; w < 16; ++w) tot += sWCnt[w];
        sBase = atomicAdd(cnt, tot);
    }
    __syncthreads();
    if (act) {
        unsigned off = sBase;
        for (int w = 0; w < wv; ++w) off += sWCnt[w];
        off += (unsigned)__popcll(mb & ((1ull << lane) - 1ull));
        idxbuf[off] = (unsigned)i;
        xc[3*off+0] = x0; xc[3*off+1] = x1; xc[3*off+2] = x2;
        dc[3*off+0] = d[3*i+0]; dc[3*off+1] = d[3*i+1]; dc[3*off+2] = d[3*i+2];
    }
}

// ---- kernel 1: hash gather, fp8 tables, no LDS staging ---------------------
// R9 theory: hash6 in-flight-saturated (Little: 0.42 ld/cy x 280cy = 118 vs
// ~125 available at 25 waves/CU; occupancy 79% from the sX __syncthreads
// ramp). Direct xc reads (L2-hot, lane-adjacent) remove the barrier -> more
// resident waves -> more loads in flight. Same per-point math.
__global__ __launch_bounds__(256) void ngp_hash7(
    const float* __restrict__ xc, const unsigned short* __restrict__ tables_pk,
    const unsigned* __restrict__ cnt, unsigned* __restrict__ feats_pk)
{
    const int NC = (int)cnt[0];
    const int j = blockIdx.x * 256 + threadIdx.x;   // compact index
    if (blockIdx.x * 256 >= NC) return;             // compacted tail: skip

    const int l = blockIdx.y;
    const float n = NLf[l];
    const unsigned short* tbl = tables_pk + (size_t)l * TSZ;

    const float xu0 = xc[3*j+0] / 3.0f + 0.5f;
    const float xu1 = xc[3*j+1] / 3.0f + 0.5f;
    const float xu2 = xc[3*j+2] / 3.0f + 0.5f;

    const float p0 = xu0 * n, p1 = xu1 * n, p2 = xu2 * n;
    const float f0 = floorf(p0), f1 = floorf(p1), f2 = floorf(p2);
    const float fr0 = p0 - f0, fr1 = p1 - f1, fr2 = p2 - f2;
    const float g0 = 1.f - fr0, g1 = 1.f - fr1, g2 = 1.f - fr2;
    const unsigned uvf0 = (unsigned)(int)f0;
    const unsigned uvc0 = (unsigned)(int)ceilf(p0);
    const unsigned syf = (unsigned)(int)f1 * 2654435761u;
    const unsigned syc = (unsigned)(int)ceilf(p1) * 2654435761u;
    const unsigned szf = (unsigned)(int)f2 * 805459861u;
    const unsigned szc = (unsigned)(int)ceilf(p2) * 805459861u;

    const float w0 = g0 * g1 * g2,  w1 = fr0 * g1 * g2;
    const float w2 = g0 * fr1 * g2, w6 = g0 * fr1 * fr2;
    const float w3 = fr0 * fr1 * g2, w5 = fr0 * g1 * fr2;
    const float w4 = g0 * g1 * fr2, w7 = fr0 * fr1 * fr2;

    const unsigned Ss[4] = { syf ^ szf, syc ^ szf, syf ^ szc, syc ^ szc };
    const float wf[4] = { w0, w2, w3, w4 };
    const float wc[4] = { w1, w6, w5, w7 };

    float a0 = 0.f, a1 = 0.f;
    #pragma unroll
    for (int pr = 0; pr < 4; ++pr) {
        const unsigned hf = (Ss[pr] ^ uvf0) & TMASK;
        const unsigned hc = (Ss[pr] ^ uvc0) & TMASK;
        const unsigned diff = hf ^ hc;
        const uint4 tv = *(const uint4*)(tbl + (hf & ~7u));   // 8 entries
        const unsigned ef = sel8(tv, hf & 7u);
        unsigned ec;
        if (diff <= 7u) ec = sel8(tv, hc & 7u);
        else            ec = (unsigned)tbl[hc];
        const v2f ff = __builtin_amdgcn_cvt_pk_f32_fp8((int)ef, false);
        const v2f fc = __builtin_amdgcn_cvt_pk_f32_fp8((int)ec, false);
        a0 = fmaf(wf[pr], ff.x, a0);
        a1 = fmaf(wf[pr], ff.y, a1);
        a0 = fmaf(wc[pr], fc.x, a0);
        a1 = fmaf(wc[pr], fc.y, a1);
    }
    a0 *= FP8INV;  // exact pow2 unscale
    a1 *= FP8INV;
    feats_pk[(size_t)l * NPTS + j] = packbf(a0, a1);
}

// ---- kernel 2: MFMA MLP, swapped-operand (transposed-D) form (R8: best) ----
#define PZ 72   // z-buffer pitch in shorts (144 B, 16B-aligned)

__global__ __launch_bounds__(512) void ngp_mlp7(
    const float* __restrict__ dc,
    const unsigned* __restrict__ feats_pk, const unsigned* __restrict__ idxbuf,
    const unsigned* __restrict__ cnt, const unsigned short* __restrict__ wpk,
    const float* __restrict__ b1a, const float* __restrict__ b1b,
    const float* __restrict__ b2a, const float* __restrict__ b2b,
    const float* __restrict__ b2c,
    float* __restrict__ out)
{
    __shared__ short sW[WPK_TOT];
    __shared__ short sZ[8 * 16 * PZ];

    const int NC = (int)cnt[0];
    if (blockIdx.x * 512 >= NC) return;       // whole block beyond compact set

    const int tid = threadIdx.x;
    for (int i = tid; i < WPK_TOT / 8; i += 512)
        ((uint4*)sW)[i] = ((const uint4*)wpk)[i];
    __syncthreads();

    const short* sW1a = sW + W1A_OFF;
    const short* sW1b = sW + W1B_OFF;
    const short* sW2a = sW + W2A_OFF;
    const short* sW2b = sW + W2B_OFF;
    const short* sW2c = sW + W2C_OFF;

    const int wave = tid >> 6, lane = tid & 63;
    const int m = lane & 15, q = lane >> 4;
    short* zb = &sZ[wave * 16 * PZ];

    // per-reg biases: reg r holds feature q*4+r (transposed-D layout)
    v4f bb1a[4], bb2a[4], bb2b[4];
    #pragma unroll
    for (int ct = 0; ct < 4; ++ct) {
        bb1a[ct] = *(const v4f*)(b1a + ct * 16 + q * 4);
        bb2a[ct] = *(const v4f*)(b2a + ct * 16 + q * 4);
        bb2b[ct] = *(const v4f*)(b2b + ct * 16 + q * 4);
    }
    const v4f bb1b4 = *(const v4f*)(b1b + q * 4);
    v4f bb2c4 = {0.f, 0.f, 0.f, 0.f};
    if (q == 0) { bb2c4[0] = b2c[0]; bb2c4[1] = b2c[1]; bb2c4[2] = b2c[2]; }

    const int base = (blockIdx.x * 8 + wave) * 64;   // 4 consecutive tiles

    for (int t = 0; t < 4; ++t) {
        const int j0 = base + t * 16;
        if (j0 >= NC) break;

        // ---- feats -> z cols [0,32) ------------------------------------
        #pragma unroll
        for (int it = 0; it < 4; ++it) {
            const int l = it * 4 + q;
            *(unsigned*)(zb + m * PZ + 2 * l) =
                feats_pk[(size_t)l * NPTS + j0 + m];
        }

        // ---- layer 1a: feats(32) -> 64, relu (swapped MFMA) ------------
        {
            const v8s z0 = *(const v8s*)(zb + m * PZ + q * 8);
            #pragma unroll
            for (int ct = 0; ct < 4; ++ct) {
                v4f acc = bb1a[ct];
                acc = MFMA16(*(const v8s*)(sW1a + (ct * 16 + m) * 40 + q * 8), z0, acc);
                const unsigned lo = cvtpk(fmaxf(acc[0], 0.f), fmaxf(acc[1], 0.f));
                const unsigned hi = cvtpk(fmaxf(acc[2], 0.f), fmaxf(acc[3], 0.f));
                *(uint2*)(zb + m * PZ + ct * 16 + q * 4) = make_uint2(lo, hi);
            }
        }

        // ---- layer 1b: 64 -> 16 (h; h[0] is log_sigma) -----------------
        {
            const v8s z0 = *(const v8s*)(zb + m * PZ + q * 8);
            const v8s z1 = *(const v8s*)(zb + m * PZ + 32 + q * 8);
            v4f hv = bb1b4;
            hv = MFMA16(*(const v8s*)(sW1b + m * 72 + q * 8), z0, hv);
            hv = MFMA16(*(const v8s*)(sW1b + m * 72 + 32 + q * 8), z1, hv);
            if (q == 0) {                     // reg 0 = feat 0 = log_sigma of point m
                const unsigned pj = idxbuf[j0 + m];
                if (pj < (unsigned)NPTS)
                    out[3 * NPTS + pj] = __expf(hv[0]);
            }
            const unsigned lo = cvtpk(hv[0], hv[1]);
            const unsigned hi = cvtpk(hv[2], hv[3]);
            *(uint2*)(zb + m * PZ + q * 4) = make_uint2(lo, hi);
        }

        // ---- posenc(dc) into z cols [16,43), zero pad [48,64) ----------
        {
            const float dd0 = dc[3*(j0+m)+0], dd1 = dc[3*(j0+m)+1], dd2 = dc[3*(j0+m)+2];
            float pv[8];
            #pragma unroll
            for (int jj = 0; jj < 8; ++jj) {
                const int k = 16 + q * 8 + jj;
                float v;
                if (k < 19) {
                    v = (k == 16) ? dd0 : ((k == 17) ? dd1 : dd2);
                } else if (k < 43) {
                    const int idx = k - 19;
                    const int e = idx / 6, w = idx - 6 * e;
                    const float base2 = (w == 0 || w == 3) ? dd0 : ((w == 1 || w == 4) ? dd1 : dd2);
                    const float s = (float)(1 << e) * base2;
                    v = (w < 3) ? __sinf(s) : __cosf(s);
                } else {
                    v = 0.f;
                }
                pv[jj] = v;
            }
            const uint4 pk4 = make_uint4(cvtpk(pv[0], pv[1]), cvtpk(pv[2], pv[3]),
                                         cvtpk(pv[4], pv[5]), cvtpk(pv[6], pv[7]));
            *(uint4*)(zb + m * PZ + 16 + q * 8) = pk4;
            *(unsigned long long*)(zb + m * PZ + 48 + q * 4) = 0ull;
        }

        // ---- layer 2a: z(43,pad64) -> 64, relu -------------------------
        {
            const v8s z0 = *(const v8s*)(zb + m * PZ + q * 8);
            const v8s z1 = *(const v8s*)(zb + m * PZ + 32 + q * 8);
            #pragma unroll
            for (int ct = 0; ct < 4; ++ct) {
                v4f acc = bb2a[ct];
                acc = MFMA16(*(const v8s*)(sW2a + (ct * 16 + m) * 72 + q * 8), z0, acc);
                acc = MFMA16(*(const v8s*)(sW2a + (ct * 16 + m) * 72 + 32 + q * 8), z1, acc);
                const unsigned lo = cvtpk(fmaxf(acc[0], 0.f), fmaxf(acc[1], 0.f));
                const unsigned hi = cvtpk(fmaxf(acc[2], 0.f), fmaxf(acc[3], 0.f));
                *(uint2*)(zb + m * PZ + ct * 16 + q * 4) = make_uint2(lo, hi);
            }
        }

        // ---- layer 2b: 64 -> 64, relu ----------------------------------
        {
            const v8s z0 = *(const v8s*)(zb + m * PZ + q * 8);
            const v8s z1 = *(const v8s*)(zb + m * PZ + 32 + q * 8);
            #pragma unroll
            for (int ct = 0; ct < 4; ++ct) {
                v4f acc = bb2b[ct];
                acc = MFMA16(*(const v8s*)(sW2b + (ct * 16 + m) * 72 + q * 8), z0, acc);
                acc = MFMA16(*(const v8s*)(sW2b + (ct * 16 + m) * 72 + 32 + q * 8), z1, acc);
                const unsigned lo = cvtpk(fmaxf(acc[0], 0.f), fmaxf(acc[1], 0.f));
                const unsigned hi = cvtpk(fmaxf(acc[2], 0.f), fmaxf(acc[3], 0.f));
                *(uint2*)(zb + m * PZ + ct * 16 + q * 4) = make_uint2(lo, hi);
            }
        }

        // ---- layer 2c: 64 -> 3, sigmoid, contiguous store --------------
        {
            const v8s z0 = *(const v8s*)(zb + m * PZ + q * 8);
            const v8s z1 = *(const v8s*)(zb + m * PZ + 32 + q * 8);
            v4f cacc = bb2c4;
            cacc = MFMA16(*(const v8s*)(sW2c + m * 72 + q * 8), z0, cacc);
            cacc = MFMA16(*(const v8s*)(sW2c + m * 72 + 32 + q * 8), z1, cacc);

            if (q == 0) {                     // regs 0..2 = color of point m
                const unsigned pj = idxbuf[j0 + m];
                if (pj < (unsigned)NPTS) {
                    out[3 * pj + 0] = 1.0f / (1.0f + __expf(-cacc[0]));
                    out[3 * pj + 1] = 1.0f / (1.0f + __expf(-cacc[1]));
                    out[3 * pj + 2] = 1.0f / (1.0f + __expf(-cacc[2]));
                }
            }
        }
    }
}

// ---------------- fallback: fused VALU kernel (if ws too small) -------------
__global__ __launch_bounds__(256) void ngp_fused(
    const float* __restrict__ x, const float* __restrict__ d,
    const float* __restrict__ tables,
    const float* __restrict__ w1a, const float* __restrict__ b1a,
    const float* __restrict__ w1b, const float* __restrict__ b1b,
    const float* __restrict__ w2a, const float* __restrict__ b2a,
    const float* __restrict__ w2b, const float* __restrict__ b2b,
    const float* __restrict__ w2c, const float* __restrict__ b2c,
    float* __restrict__ out)
{
    const int i = blockIdx.x * 256 + threadIdx.x;
    if (i >= NPTS) return;
    const float xs0 = x[3*i+0] / 3.0f;
    const float xs1 = x[3*i+1] / 3.0f;
    const float xs2 = x[3*i+2] / 3.0f;
    const bool mask = (fabsf(xs0) < 0.5f) & (fabsf(xs1) < 0.5f) & (fabsf(xs2) < 0.5f);
    const float xu0 = xs0 + 0.5f, xu1 = xs1 + 0.5f, xu2 = xs2 + 0.5f;

    float feats[32];
    #pragma unroll
    for (int l = 0; l < 16; ++l) {
        const float n = NLf[l];
        const float p0 = xu0 * n, p1 = xu1 * n, p2 = xu2 * n;
        const float f0 = floorf(p0), f1 = floorf(p1), f2 = floorf(p2);
        const float fr0 = p0 - f0, fr1 = p1 - f1, fr2 = p2 - f2;
        const int vf0 = (int)f0, vf1 = (int)f1, vf2 = (int)f2;
        const int vc0 = (int)ceilf(p0), vc1 = (int)ceilf(p1), vc2 = (int)ceilf(p2);
        const float2* tbl = (const float2*)(tables + (size_t)l * (TSZ * 2));
        float a0 = 0.f, a1 = 0.f;
        #pragma unroll
        for (int k = 0; k < 8; ++k) {
            const unsigned vx = (unsigned)(((CEILX >> k) & 1) ? vc0 : vf0);
            const unsigned vy = (unsigned)(((CEILY >> k) & 1) ? vc1 : vf1);
            const unsigned vz = (unsigned)(((CEILZ >> k) & 1) ? vc2 : vf2);
            const unsigned h = (vx ^ (vy * 2654435761u) ^ (vz * 805459861u)) & TMASK;
            const float wx = (k & 1)        ? fr0 : 1.0f - fr0;
            const float wy = ((k >> 1) & 1) ? fr1 : 1.0f - fr1;
            const float wz = ((k >> 2) & 1) ? fr2 : 1.0f - fr2;
            const float wgt = wx * wy * wz;
            const float2 t = tbl[h];
            a0 = fmaf(wgt, t.x, a0);
            a1 = fmaf(wgt, t.y, a1);
        }
        feats[2*l] = a0; feats[2*l+1] = a1;
    }

    float h2v[16];
    #pragma unroll
    for (int j = 0; j < 16; ++j) h2v[j] = b1b[j];
    #pragma unroll
    for (int c = 0; c < 4; ++c) {
        float h1c[16];
        #pragma unroll
        for (int jj = 0; jj < 16; ++jj) h1c[jj] = b1a[16*c + jj];
        #pragma unroll
        for (int i2 = 0; i2 < 32; ++i2) {
            const float f = feats[i2];
            #pragma unroll
            for (int jj = 0; jj < 16; ++jj)
                h1c[jj] = fmaf(f, w1a[i2*64 + 16*c + jj], h1c[jj]);
        }
        #pragma unroll
        for (int jj = 0; jj < 16; ++jj) {
            const float f = fmaxf(h1c[jj], 0.f);
            #pragma unroll
            for (int t = 0; t < 16; ++t)
                h2v[t] = fmaf(f, w1b[(16*c + jj)*16 + t], h2v[t]);
        }
    }

    float z1[64];
    #pragma unroll
    for (int j = 0; j < 64; ++j) z1[j] = b2a[j];
    #pragma unroll
    for (int i2 = 0; i2 < 16; ++i2) {
        const float f = h2v[i2];
        #pragma unroll
        for (int j = 0; j < 64; ++j) z1[j] = fmaf(f, w2a[i2*64 + j], z1[j]);
    }
    const float d0 = d[3*i+0], d1 = d[3*i+1], d2 = d[3*i+2];
    {
        const float* r = w2a + 16*64;
        #pragma unroll
        for (int j = 0; j < 64; ++j) z1[j] = fmaf(d0, r[j], z1[j]);
        r = w2a + 17*64;
        #pragma unroll
        for (int j = 0; j < 64; ++j) z1[j] = fmaf(d1, r[j], z1[j]);
        r = w2a + 18*64;
        #pragma unroll
        for (int j = 0; j < 64; ++j) z1[j] = fmaf(d2, r[j], z1[j]);
    }
    #pragma unroll
    for (int e = 0; e < 4; ++e) {
        const float mm = (float)(1 << e);
        const float dv[3] = {d0, d1, d2};
        #pragma unroll
        for (int a = 0; a < 3; ++a) {
            const float sv = __sinf(mm * dv[a]);
            const float* rs = w2a + (19 + 6*e + a)*64;
            #pragma unroll
            for (int j = 0; j < 64; ++j) z1[j] = fmaf(sv, rs[j], z1[j]);
        }
        #pragma unroll
        for (int a = 0; a < 3; ++a) {
            const float cv = __cosf(mm * dv[a]);
            const float* rc = w2a + (19 + 6*e + 3 + a)*64;
            #pragma unroll
            for (int j = 0; j < 64; ++j) z1[j] = fmaf(cv, rc[j], z1[j]);
        }
    }
    #pragma unroll
    for (int j = 0; j < 64; ++j) z1[j] = fmaxf(z1[j], 0.f);

    float ca = b2c[0], cb = b2c[1], cc = b2c[2];
    #pragma unroll
    for (int jc = 0; jc < 64; jc += 16) {
        float acc[16];
        #pragma unroll
        for (int jj = 0; jj < 16; ++jj) acc[jj] = b2b[jc + jj];
        #pragma unroll
        for (int i2 = 0; i2 < 64; ++i2) {
            const float f = z1[i2];
            #pragma unroll
            for (int jj = 0; jj < 16; ++jj)
                acc[jj] = fmaf(f, w2b[i2*64 + jc + jj], acc[jj]);
        }
        #pragma unroll
        for (int jj = 0; jj < 16; ++jj) {
            const float v = fmaxf(acc[jj], 0.f);
            ca = fmaf(v, w2c[(jc + jj)*3 + 0], ca);
            cb = fmaf(v, w2c[(jc + jj)*3 + 1], cb);
            cc = fmaf(v, w2c[(jc + jj)*3 + 2], cc);
        }
    }

    float r = 1.0f / (1.0f + __expf(-ca));
    float g = 1.0f / (1.0f + __expf(-cb));
    float b = 1.0f / (1.0f + __expf(-cc));
    float sigma;
    if (mask) { sigma = __expf(h2v[0]); }
    else { r = 0.f; g = 0.f; b = 0.f; sigma = 0.f; }
    out[3*i + 0] = r;
    out[3*i + 1] = g;
    out[3*i + 2] = b;
    out[3*NPTS + i] = sigma;
}

extern "C" void kernel_launch(void* const* d_in, const int* in_sizes, int n_in,
                              void* d_out, int out_size, void* d_ws, size_t ws_size,
                              hipStream_t stream) {
    const float* x      = (const float*)d_in[0];
    const float* d      = (const float*)d_in[1];
    const float* tables = (const float*)d_in[2];
    const float* w1a    = (const float*)d_in[3];
    const float* b1a    = (const float*)d_in[4];
    const float* w1b    = (const float*)d_in[5];
    const float* b1b    = (const float*)d_in[6];
    const float* w2a    = (const float*)d_in[7];
    const float* b2a    = (const float*)d_in[8];
    const float* w2b    = (const float*)d_in[9];
    const float* b2b    = (const float*)d_in[10];
    const float* w2c    = (const float*)d_in[11];
    const float* b2c    = (const float*)d_in[12];
    float* out = (float*)d_out;

    // ws layout (u32 units): [0,16N) feats_pk; [16N,24N) tables_pk (fp8 2B/e);
    // [24N,25N) idxbuf; [25N] counter; [26N,29N) xc; [29N,32N) dc;
    // [32N, 32N+7040) wpk (bf16 weights)
    const size_t need = (size_t)33 * NPTS * 4;   // 66 MiB
    if (ws_size >= need) {
        unsigned* base      = (unsigned*)d_ws;
        unsigned* feats_pk  = base;
        unsigned* tables_pk = base + (size_t)16 * NPTS;
        unsigned* idxbuf    = base + (size_t)24 * NPTS;
        unsigned* cnt       = base + (size_t)25 * NPTS;
        float*    xc        = (float*)(base + (size_t)26 * NPTS);
        float*    dc        = (float*)(base + (size_t)29 * NPTS);
        unsigned short* wpk = (unsigned short*)(base + (size_t)32 * NPTS);

        // stream-ordered init BEFORE prologue (fixes R9's sentinel race):
        hipMemsetAsync(cnt, 0, 4, stream);
        hipMemsetAsync(idxbuf, 0xFF, (size_t)NPTS * 4, stream);

        dim3 gpro(NPTS / 1024), bpro(1024);
        hipLaunchKernelGGL(ngp_prologue, gpro, bpro, 0, stream,
                           x, d, (const float4*)tables, w1a, w1b, w2a, w2b, w2c,
                           tables_pk, wpk, idxbuf, xc, dc, cnt, out);

        dim3 gh(NPTS / 256, 16), bh(256);
        hipLaunchKernelGGL(ngp_hash7, gh, bh, 0, stream,
                           xc, (const unsigned short*)tables_pk, cnt, feats_pk);

        dim3 gm(NPTS / 512), bm(512);
        hipLaunchKernelGGL(ngp_mlp7, gm, bm, 0, stream,
                           dc, feats_pk, idxbuf, cnt, wpk,
                           b1a, b1b, b2a, b2b, b2c, out);
    } else {
        dim3 grid(NPTS / 256), block(256);
        hipLaunchKernelGGL(ngp_fused, grid, block, 0, stream,
                           x, d, tables, w1a, b1a, w1b, b1b,
                           w2a, b2a, w2b, b2b, w2c, b2c, out);
    }
}